// Round 3
// baseline (295.494 us; speedup 1.0000x reference)
//
#include <hip/hip_runtime.h>
#include <stdint.h>

// N=2048, M=128, D_IN=352, H1=512, D=256, OUT_C=13.  All device tensors are FLOAT32
// (reference dtypes; previous NaN rounds were f32-read-as-bf16 garbage).
// Algebra: diff = A[n]-B[m] is affine -> fold conv1 of the SharedMLP into
// PA2[n,32], PB2[m,32]; softmax over m sums to 1 -> att[n,c] = A[n,c] - sum_m wei*B[m,c].

typedef __attribute__((ext_vector_type(4))) float float4_t;
typedef __attribute__((ext_vector_type(8))) unsigned short ushort8_t;
typedef __attribute__((ext_vector_type(4))) unsigned short ushort4_t;

__device__ __forceinline__ float b2f(unsigned short u) {
  union { unsigned int i; float f; } v; v.i = ((unsigned int)u) << 16; return v.f;
}
__device__ __forceinline__ unsigned short f2b(float f) {
  union { float f; unsigned int i; } v; v.f = f;
  unsigned int x = v.i;
  return (unsigned short)((x + 0x7FFFu + ((x >> 16) & 1u)) >> 16);
}

// ---------- encode GEMM (f32): Y = relu(g*(X @ W^T + b) + be) ----------
#define GTF 68  // padded LDS row stride in floats (272B rows: b128-aligned, bank-spread)

__global__ __launch_bounds__(256) void gemm_bn_relu(
    const float* __restrict__ X, const float* __restrict__ W,
    const float* __restrict__ bb, const float* __restrict__ gg,
    const float* __restrict__ bev, float* __restrict__ Y,
    int I, int J, int K)
{
  __shared__ float Xt[32][GTF];
  __shared__ float Wt[32][GTF];
  const int tid = threadIdx.x;
  const int i0 = blockIdx.x * 64, j0 = blockIdx.y * 64;
  const int li = tid >> 4, lj = tid & 15;     // 16x16 thread grid, 4x4 microtile
  const int sr = tid >> 2, sk = (tid & 3) * 8;
  float acc[4][4] = {};
  for (int kt = 0; kt < K; kt += 32) {
    const float* xp = &X[(size_t)(i0 + sr) * K + kt + sk];
    const float* wp = &W[(size_t)(j0 + sr) * K + kt + sk];
    float4_t x0 = *(const float4_t*)xp;
    float4_t x1 = *(const float4_t*)(xp + 4);
    float4_t w0 = *(const float4_t*)wp;
    float4_t w1 = *(const float4_t*)(wp + 4);
    __syncthreads();
    #pragma unroll
    for (int q = 0; q < 4; ++q) {
      Xt[sk + q][sr] = x0[q]; Xt[sk + 4 + q][sr] = x1[q];
      Wt[sk + q][sr] = w0[q]; Wt[sk + 4 + q][sr] = w1[q];
    }
    __syncthreads();
    #pragma unroll 8
    for (int k = 0; k < 32; ++k) {
      float xf[4], wf[4];
      #pragma unroll
      for (int e = 0; e < 4; ++e) { xf[e] = Xt[k][li * 4 + e]; wf[e] = Wt[k][lj * 4 + e]; }
      #pragma unroll
      for (int a = 0; a < 4; ++a)
        #pragma unroll
        for (int c = 0; c < 4; ++c)
          acc[a][c] = fmaf(xf[a], wf[c], acc[a][c]);
    }
  }
  #pragma unroll
  for (int a = 0; a < 4; ++a) {
    const int row = i0 + li * 4 + a;
    #pragma unroll
    for (int c = 0; c < 4; ++c) {
      const int col = j0 + lj * 4 + c;
      float t = acc[a][c] + bb[col];
      t = gg[col] * t + bev[col];
      Y[(size_t)row * J + col] = fmaxf(t, 0.f);
    }
  }
}

// ---------- PA2/PB2: P = fold(X @ mw1^T); X [I,256] f32, mw1 [32,256] f32 ----------
__global__ __launch_bounds__(256) void proj32(
    const float* __restrict__ X, const float* __restrict__ mw1,
    const float* __restrict__ mb1, const float* __restrict__ mg1,
    const float* __restrict__ mbe1, float* __restrict__ P, int withBias)
{
  const int tid = threadIdx.x;
  const int r = tid >> 5, k = tid & 31;
  const int n = blockIdx.x * 8 + r;
  const float* xp = &X[(size_t)n * 256];
  const float* wp = &mw1[k * 256];
  float s = 0.f;
  #pragma unroll 8
  for (int q = 0; q < 256; q += 4) {
    float4_t xv = *(const float4_t*)&xp[q];
    float4_t wv = *(const float4_t*)&wp[q];
    #pragma unroll
    for (int e = 0; e < 4; ++e) s = fmaf(xv[e], wv[e], s);
  }
  P[(size_t)n * 32 + k] = withBias ? (mg1[k] * (s + mb1[k]) + mbe1[k]) : (mg1[k] * s);
}

// ---------- fused main kernel: one block per n ----------
// LDS map (60KB): [0,8K) h1T[32][128] bf16 | [8K,12K) w2T[32][64] bf16
//                 [12K,28K) h2T[64][128] bf16 | [28K,60K) w3T[64][256] bf16
// After a barrier post-phase2, dead w3T region reused:
//                 [28K,32K) pmx | [32K,36K) ps | [36K,40K) pwb | [40K,41K) attL (f32)
__global__ __launch_bounds__(256, 2) void main_attn(
    const float* __restrict__ PA2, const float* __restrict__ PB2,
    const float* __restrict__ A, const float* __restrict__ Bm,
    const float* __restrict__ mw2, const float* __restrict__ mb2,
    const float* __restrict__ mg2, const float* __restrict__ mbe2,
    const float* __restrict__ mw3, const float* __restrict__ mb3,
    const float* __restrict__ mg3, const float* __restrict__ mbe3,
    const float* __restrict__ fcw, const float* __restrict__ fcb,
    float* __restrict__ outp)
{
  __shared__ __align__(16) char smem[60 * 1024];
  unsigned short* h1T = (unsigned short*)smem;                 // [32][128]
  unsigned short* w2T = (unsigned short*)(smem + 8 * 1024);    // [32][64]
  unsigned short* h2T = (unsigned short*)(smem + 12 * 1024);   // [64][128]
  unsigned short* w3T = (unsigned short*)(smem + 28 * 1024);   // [64][256]
  const int tid = threadIdx.x;
  const int n = blockIdx.x;

  // stage w3T (transpose mw3 [256][64] -> [64][256]) and w2T ([64][32] -> [32][64]), f32->bf16
  {
    const int c = tid;
    #pragma unroll
    for (int q = 0; q < 16; ++q) {
      float4_t v = *(const float4_t*)&mw3[c * 64 + q * 4];
      #pragma unroll
      for (int e = 0; e < 4; ++e) w3T[(q * 4 + e) * 256 + c] = f2b(v[e]);
    }
    if (tid < 64) {
      #pragma unroll
      for (int q = 0; q < 8; ++q) {
        float4_t v = *(const float4_t*)&mw2[tid * 32 + q * 4];
        #pragma unroll
        for (int e = 0; e < 4; ++e) w2T[(q * 4 + e) * 64 + tid] = f2b(v[e]);
      }
    }
  }
  // phase0: h1T[k][m] = relu(PA2[n][k] - PB2[m][k])
  {
    const int m = tid & 127, kh = (tid >> 7) * 16;
    const float* pb = &PB2[m * 32 + kh];
    const float* pa = &PA2[n * 32 + kh];
    #pragma unroll
    for (int q = 0; q < 16; ++q)
      h1T[(kh + q) * 128 + m] = f2b(fmaxf(pa[q] - pb[q], 0.f));
  }
  __syncthreads();

  // phase1: h2[m][j] = relu(g2*(h1 @ mw2^T + b2) + be2) -> h2T[j][m]
  {
    const int jb = tid & 15, mgr1 = tid >> 4;
    const int j0 = jb * 4, m0 = mgr1 * 8;
    float acc1[8][4] = {};
    #pragma unroll 2
    for (int k = 0; k < 32; ++k) {
      ushort8_t hv = *(const ushort8_t*)&h1T[k * 128 + m0];
      ushort4_t wv = *(const ushort4_t*)&w2T[k * 64 + j0];
      float hf[8], wf[4];
      #pragma unroll
      for (int e = 0; e < 8; ++e) hf[e] = b2f(hv[e]);
      #pragma unroll
      for (int e = 0; e < 4; ++e) wf[e] = b2f(wv[e]);
      #pragma unroll
      for (int mi = 0; mi < 8; ++mi)
        #pragma unroll
        for (int jj = 0; jj < 4; ++jj)
          acc1[mi][jj] = fmaf(hf[mi], wf[jj], acc1[mi][jj]);
    }
    #pragma unroll
    for (int jj = 0; jj < 4; ++jj) {
      const int j = j0 + jj;
      const float g = mg2[j], bv = mb2[j], ev = mbe2[j];
      #pragma unroll
      for (int mi = 0; mi < 8; mi += 2) {
        float v0 = fmaxf(g * (acc1[mi][jj] + bv) + ev, 0.f);
        float v1 = fmaxf(g * (acc1[mi + 1][jj] + bv) + ev, 0.f);
        unsigned int pk = (unsigned int)f2b(v0) | ((unsigned int)f2b(v1) << 16);
        *(unsigned int*)&h2T[j * 128 + m0 + mi] = pk;
      }
    }
  }
  __syncthreads();

  // phase2: logits[m][c] = relu(g3*(h2 @ mw3^T + b3) + be3); microtile 8m x 16c / thread
  const int cb = tid & 15, mgr = tid >> 4;
  const int c0 = cb * 16, m0 = mgr * 8;
  float acc[8][16];
  #pragma unroll
  for (int mi = 0; mi < 8; ++mi)
    #pragma unroll
    for (int cc = 0; cc < 16; ++cc) acc[mi][cc] = 0.f;
  #pragma unroll 2
  for (int k = 0; k < 64; ++k) {
    ushort8_t hv = *(const ushort8_t*)&h2T[k * 128 + m0];
    ushort8_t w0 = *(const ushort8_t*)&w3T[k * 256 + c0];
    ushort8_t w1 = *(const ushort8_t*)&w3T[k * 256 + c0 + 8];
    float hf[8], wf[16];
    #pragma unroll
    for (int e = 0; e < 8; ++e) hf[e] = b2f(hv[e]);
    #pragma unroll
    for (int e = 0; e < 8; ++e) { wf[e] = b2f(w0[e]); wf[8 + e] = b2f(w1[e]); }
    #pragma unroll
    for (int mi = 0; mi < 8; ++mi)
      #pragma unroll
      for (int cc = 0; cc < 16; ++cc)
        acc[mi][cc] = fmaf(hf[mi], wf[cc], acc[mi][cc]);
  }
  // BN+ReLU, then per-thread softmax partial over its 8 m (two-pass)
  float mx[16], sm[16], wb[16];
  #pragma unroll
  for (int cc = 0; cc < 16; ++cc) {
    const int c = c0 + cc;
    const float g = mg3[c], bv = mb3[c], ev = mbe3[c];
    float m_ = 0.f;  // logits are relu'd -> >= 0
    #pragma unroll
    for (int mi = 0; mi < 8; ++mi) {
      float l = fmaxf(g * (acc[mi][cc] + bv) + ev, 0.f);
      acc[mi][cc] = l;
      m_ = fmaxf(m_, l);
    }
    mx[cc] = m_; sm[cc] = 0.f; wb[cc] = 0.f;
  }
  #pragma unroll
  for (int mi = 0; mi < 8; ++mi) {
    const int m = m0 + mi;
    const float* bp = &Bm[(size_t)m * 256 + c0];
    float4_t b0 = *(const float4_t*)bp;
    float4_t b1 = *(const float4_t*)(bp + 4);
    float4_t b2 = *(const float4_t*)(bp + 8);
    float4_t b3 = *(const float4_t*)(bp + 12);
    float bvv[16];
    #pragma unroll
    for (int e = 0; e < 4; ++e) {
      bvv[e] = b0[e]; bvv[4 + e] = b1[e]; bvv[8 + e] = b2[e]; bvv[12 + e] = b3[e];
    }
    #pragma unroll
    for (int cc = 0; cc < 16; ++cc) {
      float p = __expf(fminf(acc[mi][cc] - mx[cc], 0.f));
      sm[cc] += p;
      wb[cc] += p * bvv[cc];
    }
  }
  // merge the 4 m-groups within each wave (lanes ^16, ^32 share cb)
  #pragma unroll
  for (int st = 16; st <= 32; st <<= 1) {
    #pragma unroll
    for (int cc = 0; cc < 16; ++cc) {
      float omx = __shfl_xor(mx[cc], st, 64);
      float osm = __shfl_xor(sm[cc], st, 64);
      float owb = __shfl_xor(wb[cc], st, 64);
      float nm = fmaxf(mx[cc], omx);
      float e1 = __expf(fminf(mx[cc] - nm, 0.f)), e2 = __expf(fminf(omx - nm, 0.f));
      sm[cc] = sm[cc] * e1 + osm * e2;
      wb[cc] = wb[cc] * e1 + owb * e2;
      mx[cc] = nm;
    }
  }

  // ALL waves done with h2T/w3T only after this barrier -> reuse w3T region.
  __syncthreads();
  float* pmx  = (float*)(smem + 28 * 1024);
  float* ps   = (float*)(smem + 32 * 1024);
  float* pwb  = (float*)(smem + 36 * 1024);
  float* attL = (float*)(smem + 40 * 1024);

  if ((tid & 63) < 16) {  // lane<16 of each wave holds the wave-merged partial for its cb
    const int w = tid >> 6;
    #pragma unroll
    for (int cc = 0; cc < 16; ++cc) {
      const int c = c0 + cc;
      pmx[w * 256 + c] = mx[cc];
      ps [w * 256 + c] = sm[cc];
      pwb[w * 256 + c] = wb[cc];
    }
  }
  __syncthreads();
  // final merge across the 4 waves; att[c] = A[n][c] - wb/s
  {
    const int c = tid;
    float M = pmx[c], S = ps[c], Wv = pwb[c];
    #pragma unroll
    for (int w = 1; w < 4; ++w) {
      float m1 = pmx[w * 256 + c], s1 = ps[w * 256 + c], w1 = pwb[w * 256 + c];
      float nm = fmaxf(M, m1);
      float e0 = __expf(fminf(M - nm, 0.f)), e1 = __expf(fminf(m1 - nm, 0.f));
      S = S * e0 + s1 * e1;
      Wv = Wv * e0 + w1 * e1;
      M = nm;
    }
    attL[c] = A[(size_t)n * 256 + c] - Wv / fmaxf(S, 1e-30f);
  }
  __syncthreads();
  if (tid < 13) {
    float s = fcb[tid];
    for (int c = 0; c < 256; ++c) s = fmaf(attL[c], fcw[tid * 256 + c], s);
    outp[(size_t)n * 13 + tid] = s;
  }
}

extern "C" void kernel_launch(void* const* d_in, const int* in_sizes, int n_in,
                              void* d_out, int out_size, void* d_ws, size_t ws_size,
                              hipStream_t stream)
{
  const float* ext = (const float*)d_in[0];
  const float* lab = (const float*)d_in[1];
  const float* w1a = (const float*)d_in[2];
  const float* b1a = (const float*)d_in[3];
  const float* g1a = (const float*)d_in[4];
  const float* be1a= (const float*)d_in[5];
  const float* w1b = (const float*)d_in[6];
  const float* b1b = (const float*)d_in[7];
  const float* g1b = (const float*)d_in[8];
  const float* be1b= (const float*)d_in[9];
  const float* w2a = (const float*)d_in[10];
  const float* b2a = (const float*)d_in[11];
  const float* g2a = (const float*)d_in[12];
  const float* be2a= (const float*)d_in[13];
  const float* w2b = (const float*)d_in[14];
  const float* b2b = (const float*)d_in[15];
  const float* g2b = (const float*)d_in[16];
  const float* be2b= (const float*)d_in[17];
  const float* mw1 = (const float*)d_in[18];
  const float* mb1 = (const float*)d_in[19];
  const float* mg1 = (const float*)d_in[20];
  const float* mbe1= (const float*)d_in[21];
  const float* mw2 = (const float*)d_in[22];
  const float* mb2 = (const float*)d_in[23];
  const float* mg2 = (const float*)d_in[24];
  const float* mbe2= (const float*)d_in[25];
  const float* mw3 = (const float*)d_in[26];
  const float* mb3 = (const float*)d_in[27];
  const float* mg3 = (const float*)d_in[28];
  const float* mbe3= (const float*)d_in[29];
  const float* fcw = (const float*)d_in[30];
  const float* fcb = (const float*)d_in[31];

  // ws (f32), peak 6MB: Y1a@[0,4M) transient; Aenc@[4M,6M) persistent;
  // after Y1a dies: Y1b@[0,256K), Benc@[256K,384K), PA2@[384K,640K), PB2@[640K,656K).
  char* ws = (char*)d_ws;
  float* Y1a  = (float*)(ws);                     // 2048x512 f32
  float* Aenc = (float*)(ws + (4u << 20));        // 2048x256 f32
  float* Y1b  = (float*)(ws);                     // 128x512 f32 (reuse of dead Y1a)
  float* Benc = (float*)(ws + (256u << 10));      // 128x256 f32
  float* PA2  = (float*)(ws + (384u << 10));      // 2048x32 f32
  float* PB2  = (float*)(ws + (640u << 10));      // 128x32 f32

  gemm_bn_relu<<<dim3(32, 8), 256, 0, stream>>>(ext, w1a, b1a, g1a, be1a, Y1a, 2048, 512, 352);
  gemm_bn_relu<<<dim3(32, 4), 256, 0, stream>>>(Y1a, w1b, b1b, g1b, be1b, Aenc, 2048, 256, 512);
  gemm_bn_relu<<<dim3(2, 8),  256, 0, stream>>>(lab, w2a, b2a, g2a, be2a, Y1b, 128, 512, 352);
  gemm_bn_relu<<<dim3(2, 4),  256, 0, stream>>>(Y1b, w2b, b2b, g2b, be2b, Benc, 128, 256, 512);
  proj32<<<256, 256, 0, stream>>>(Aenc, mw1, mb1, mg1, mbe1, PA2, 1);
  proj32<<<16, 256, 0, stream>>>(Benc, mw1, mb1, mg1, mbe1, PB2, 0);
  main_attn<<<2048, 256, 0, stream>>>(PA2, PB2, Aenc, Benc,
                                      mw2, mb2, mg2, mbe2, mw3, mb3, mg3, mbe3,
                                      fcw, fcb, (float*)d_out);
}

// Round 4
// 198.254 us; speedup vs baseline: 1.4905x; 1.4905x over previous
//
#include <hip/hip_runtime.h>
#include <stdint.h>

// N=2048, M=128, D_IN=352, H1=512, D=256, OUT_C=13.  All device tensors FLOAT32.
// Algebra: diff = A[n]-B[m] is affine -> fold conv1 of the SharedMLP into
// PA2[n,32], PB2[m,32]; softmax over m sums to 1 -> att[n,c] = A[n,c] - sum_m wei*B[m,c].
// Round 4: main_attn phases 1&2 on MFMA (mfma_f32_16x16x32_bf16), softmax in-register.

typedef __attribute__((ext_vector_type(4))) float float4_t;
typedef __attribute__((ext_vector_type(4))) float f32x4;
typedef __attribute__((ext_vector_type(8))) short bf16x8;
typedef __attribute__((ext_vector_type(8))) unsigned short ushort8_t;
typedef unsigned short ushort_t;

__device__ __forceinline__ float b2f(unsigned short u) {
  union { unsigned int i; float f; } v; v.i = ((unsigned int)u) << 16; return v.f;
}
__device__ __forceinline__ unsigned short f2b(float f) {
  union { float f; unsigned int i; } v; v.f = f;
  unsigned int x = v.i;
  return (unsigned short)((x + 0x7FFFu + ((x >> 16) & 1u)) >> 16);
}

// ---------- encode GEMM (f32): Y = relu(g*(X @ W^T + b) + be) ----------
#define GTF 68

__global__ __launch_bounds__(256) void gemm_bn_relu(
    const float* __restrict__ X, const float* __restrict__ W,
    const float* __restrict__ bb, const float* __restrict__ gg,
    const float* __restrict__ bev, float* __restrict__ Y,
    int I, int J, int K)
{
  __shared__ float Xt[32][GTF];
  __shared__ float Wt[32][GTF];
  const int tid = threadIdx.x;
  const int i0 = blockIdx.x * 64, j0 = blockIdx.y * 64;
  const int li = tid >> 4, lj = tid & 15;
  const int sr = tid >> 2, sk = (tid & 3) * 8;
  float acc[4][4] = {};
  for (int kt = 0; kt < K; kt += 32) {
    const float* xp = &X[(size_t)(i0 + sr) * K + kt + sk];
    const float* wp = &W[(size_t)(j0 + sr) * K + kt + sk];
    float4_t x0 = *(const float4_t*)xp;
    float4_t x1 = *(const float4_t*)(xp + 4);
    float4_t w0 = *(const float4_t*)wp;
    float4_t w1 = *(const float4_t*)(wp + 4);
    __syncthreads();
    #pragma unroll
    for (int q = 0; q < 4; ++q) {
      Xt[sk + q][sr] = x0[q]; Xt[sk + 4 + q][sr] = x1[q];
      Wt[sk + q][sr] = w0[q]; Wt[sk + 4 + q][sr] = w1[q];
    }
    __syncthreads();
    #pragma unroll 8
    for (int k = 0; k < 32; ++k) {
      float xf[4], wf[4];
      #pragma unroll
      for (int e = 0; e < 4; ++e) { xf[e] = Xt[k][li * 4 + e]; wf[e] = Wt[k][lj * 4 + e]; }
      #pragma unroll
      for (int a = 0; a < 4; ++a)
        #pragma unroll
        for (int c = 0; c < 4; ++c)
          acc[a][c] = fmaf(xf[a], wf[c], acc[a][c]);
    }
  }
  #pragma unroll
  for (int a = 0; a < 4; ++a) {
    const int row = i0 + li * 4 + a;
    #pragma unroll
    for (int c = 0; c < 4; ++c) {
      const int col = j0 + lj * 4 + c;
      float t = acc[a][c] + bb[col];
      t = gg[col] * t + bev[col];
      Y[(size_t)row * J + col] = fmaxf(t, 0.f);
    }
  }
}

// ---------- PA2/PB2: P = fold(X @ mw1^T) ----------
__global__ __launch_bounds__(256) void proj32(
    const float* __restrict__ X, const float* __restrict__ mw1,
    const float* __restrict__ mb1, const float* __restrict__ mg1,
    const float* __restrict__ mbe1, float* __restrict__ P, int withBias)
{
  const int tid = threadIdx.x;
  const int r = tid >> 5, k = tid & 31;
  const int n = blockIdx.x * 8 + r;
  const float* xp = &X[(size_t)n * 256];
  const float* wp = &mw1[k * 256];
  float s = 0.f;
  #pragma unroll 8
  for (int q = 0; q < 256; q += 4) {
    float4_t xv = *(const float4_t*)&xp[q];
    float4_t wv = *(const float4_t*)&wp[q];
    #pragma unroll
    for (int e = 0; e < 4; ++e) s = fmaf(xv[e], wv[e], s);
  }
  P[(size_t)n * 32 + k] = withBias ? (mg1[k] * (s + mb1[k]) + mbe1[k]) : (mg1[k] * s);
}

// ---------- fused main kernel (MFMA): one block per n, 4 waves ----------
// MFMA 16x16x32_bf16 layouts (learn_hip m89-verified family):
//   A frag: m = lane&15, k = (lane>>4)*8 + e (8 contiguous k -> one b128 read)
//   B frag: c = lane&15, k = (lane>>4)*8 + e
//   C/D:    col = lane&15, row = (lane>>4)*4 + reg
// LDS (bytes): [0,36864) w3s[256][72] bf16 | [36864,47104) h1s[128][40] bf16
//              [47104,52224) w2s[64][40] bf16
// after phase1 barrier: [36864,55296) h2s[128][72] bf16 (overwrites h1s+w2s)
// after phase2 barrier: [0,1024) attL[256] f32 | [1024,1856) part[208] f32
__global__ __launch_bounds__(256, 2) void main_attn(
    const float* __restrict__ PA2, const float* __restrict__ PB2,
    const float* __restrict__ A, const float* __restrict__ Bm,
    const float* __restrict__ mw2, const float* __restrict__ mb2,
    const float* __restrict__ mg2, const float* __restrict__ mbe2,
    const float* __restrict__ mw3, const float* __restrict__ mb3,
    const float* __restrict__ mg3, const float* __restrict__ mbe3,
    const float* __restrict__ fcw, const float* __restrict__ fcb,
    float* __restrict__ outp)
{
  __shared__ __align__(16) char smem[56 * 1024];
  ushort_t* w3s = (ushort_t*)smem;                   // [256][72]
  ushort_t* h1s = (ushort_t*)(smem + 36864);         // [128][40]
  ushort_t* w2s = (ushort_t*)(smem + 47104);         // [64][40]
  ushort_t* h2s = (ushort_t*)(smem + 36864);         // [128][72] (phase-disjoint)
  float* attL = (float*)smem;                        // [256]   (phase-disjoint)
  float* part = (float*)(smem + 1024);               // [208]

  const int tid = threadIdx.x;
  const int w = tid >> 6, lane = tid & 63, lg = lane >> 4, lr = lane & 15;
  const int n = blockIdx.x;

  // ---- stage w3s: mw3[256][64] f32 -> w3s[c][72] bf16 (row-copy per thread) ----
  {
    const int c = tid;
    const float* src = &mw3[c * 64];
    #pragma unroll
    for (int q = 0; q < 8; ++q) {
      float4_t v0 = *(const float4_t*)&src[q * 8];
      float4_t v1 = *(const float4_t*)&src[q * 8 + 4];
      ushort8_t u;
      #pragma unroll
      for (int e = 0; e < 4; ++e) { u[e] = f2b(v0[e]); u[4 + e] = f2b(v1[e]); }
      *(ushort8_t*)&w3s[c * 72 + q * 8] = u;
    }
  }
  // ---- stage w2s: mw2[64][32] f32 -> w2s[j][40] bf16 ----
  if (tid < 64) {
    const float* src = &mw2[tid * 32];
    #pragma unroll
    for (int q = 0; q < 4; ++q) {
      float4_t v0 = *(const float4_t*)&src[q * 8];
      float4_t v1 = *(const float4_t*)&src[q * 8 + 4];
      ushort8_t u;
      #pragma unroll
      for (int e = 0; e < 4; ++e) { u[e] = f2b(v0[e]); u[4 + e] = f2b(v1[e]); }
      *(ushort8_t*)&w2s[tid * 40 + q * 8] = u;
    }
  }
  // ---- phase0: h1s[m][k] = relu(PA2[n][k] - PB2[m][k]), bf16 ----
  {
    const int m = tid >> 1, half = tid & 1;
    const float* pa = &PA2[(size_t)n * 32 + half * 16];
    const float* pb = &PB2[(size_t)m * 32 + half * 16];
    #pragma unroll
    for (int q = 0; q < 2; ++q) {
      float4_t a0 = *(const float4_t*)&pa[q * 8];
      float4_t a1 = *(const float4_t*)&pa[q * 8 + 4];
      float4_t b0 = *(const float4_t*)&pb[q * 8];
      float4_t b1 = *(const float4_t*)&pb[q * 8 + 4];
      ushort8_t u;
      #pragma unroll
      for (int e = 0; e < 4; ++e) {
        u[e]     = f2b(fmaxf(a0[e] - b0[e], 0.f));
        u[4 + e] = f2b(fmaxf(a1[e] - b1[e], 0.f));
      }
      *(ushort8_t*)&h1s[m * 40 + half * 16 + q * 8] = u;
    }
  }
  __syncthreads();

  // ---- phase1 (MFMA): h2[m][j] = relu(g2*(h1 @ mw2^T + b2) + be2) ----
  // wave w owns m in [w*32, w*32+32): 2 m-tiles x 4 j-tiles, K=32 (one step)
  ushort_t h2o[2][4][4];
  {
    f32x4 acc1[2][4];
    #pragma unroll
    for (int mt = 0; mt < 2; ++mt)
      #pragma unroll
      for (int jt = 0; jt < 4; ++jt) acc1[mt][jt] = f32x4{0.f, 0.f, 0.f, 0.f};
    bf16x8 a1[2], b1[4];
    #pragma unroll
    for (int mt = 0; mt < 2; ++mt)
      a1[mt] = *(const bf16x8*)&h1s[(w * 32 + mt * 16 + lr) * 40 + lg * 8];
    #pragma unroll
    for (int jt = 0; jt < 4; ++jt)
      b1[jt] = *(const bf16x8*)&w2s[(jt * 16 + lr) * 40 + lg * 8];
    #pragma unroll
    for (int mt = 0; mt < 2; ++mt)
      #pragma unroll
      for (int jt = 0; jt < 4; ++jt)
        acc1[mt][jt] = __builtin_amdgcn_mfma_f32_16x16x32_bf16(a1[mt], b1[jt], acc1[mt][jt], 0, 0, 0);
    // bn2 + relu -> bf16 in regs (j = jt*16+lr per lane; m = w*32+mt*16+4*lg+r)
    #pragma unroll
    for (int jt = 0; jt < 4; ++jt) {
      const int j = jt * 16 + lr;
      const float g = mg2[j], bv = mb2[j], ev = mbe2[j];
      #pragma unroll
      for (int mt = 0; mt < 2; ++mt)
        #pragma unroll
        for (int r = 0; r < 4; ++r)
          h2o[mt][jt][r] = f2b(fmaxf(g * (acc1[mt][jt][r] + bv) + ev, 0.f));
    }
  }
  __syncthreads();   // all phase1 LDS reads complete -> safe to overwrite h1s/w2s
  #pragma unroll
  for (int mt = 0; mt < 2; ++mt)
    #pragma unroll
    for (int jt = 0; jt < 4; ++jt)
      #pragma unroll
      for (int r = 0; r < 4; ++r)
        h2s[(w * 32 + mt * 16 + 4 * lg + r) * 72 + jt * 16 + lr] = h2o[mt][jt][r];
  __syncthreads();

  // ---- phase2 (MFMA): logits[m][c] = relu(g3*(h2 @ mw3^T + b3) + be3) ----
  // wave w owns c in [w*64, w*64+64): 8 m-tiles x 4 c-tiles x 2 K-steps
  f32x4 acc[8][4];
  #pragma unroll
  for (int mt = 0; mt < 8; ++mt)
    #pragma unroll
    for (int ct = 0; ct < 4; ++ct) acc[mt][ct] = f32x4{0.f, 0.f, 0.f, 0.f};
  #pragma unroll
  for (int ks = 0; ks < 2; ++ks) {
    bf16x8 bfr[4];
    #pragma unroll
    for (int ct = 0; ct < 4; ++ct)
      bfr[ct] = *(const bf16x8*)&w3s[(w * 64 + ct * 16 + lr) * 72 + ks * 32 + lg * 8];
    #pragma unroll
    for (int mt = 0; mt < 8; ++mt) {
      bf16x8 af = *(const bf16x8*)&h2s[(mt * 16 + lr) * 72 + ks * 32 + lg * 8];
      #pragma unroll
      for (int ct = 0; ct < 4; ++ct)
        acc[mt][ct] = __builtin_amdgcn_mfma_f32_16x16x32_bf16(af, bfr[ct], acc[mt][ct], 0, 0, 0);
    }
  }

  // ---- bn3+relu+softmax, all in registers; column c is lane-local ----
  float mxv[4], smv[4], wbv[4];
  #pragma unroll
  for (int ct = 0; ct < 4; ++ct) {
    const int c = w * 64 + ct * 16 + lr;
    const float g = mg3[c], bv = mb3[c], ev = mbe3[c];
    float mx = 0.f;
    #pragma unroll
    for (int mt = 0; mt < 8; ++mt)
      #pragma unroll
      for (int r = 0; r < 4; ++r) {
        float l = fmaxf(g * (acc[mt][ct][r] + bv) + ev, 0.f);
        acc[mt][ct][r] = l;
        mx = fmaxf(mx, l);
      }
    float sm = 0.f, wb = 0.f;
    #pragma unroll
    for (int mt = 0; mt < 8; ++mt)
      #pragma unroll
      for (int r = 0; r < 4; ++r) {
        const int m = mt * 16 + 4 * lg + r;
        float p = __expf(acc[mt][ct][r] - mx);
        float bval = Bm[(size_t)m * 256 + c];
        sm += p;
        wb = fmaf(p, bval, wb);
      }
    mxv[ct] = mx; smv[ct] = sm; wbv[ct] = wb;
  }
  // merge the 4 lane-groups (m-partition) via xor on lane bits 4,5
  #pragma unroll
  for (int st = 16; st <= 32; st <<= 1) {
    #pragma unroll
    for (int ct = 0; ct < 4; ++ct) {
      float omx = __shfl_xor(mxv[ct], st, 64);
      float osm = __shfl_xor(smv[ct], st, 64);
      float owb = __shfl_xor(wbv[ct], st, 64);
      float nm = fmaxf(mxv[ct], omx);
      float e0 = __expf(mxv[ct] - nm), e1 = __expf(omx - nm);
      smv[ct] = smv[ct] * e0 + osm * e1;
      wbv[ct] = wbv[ct] * e0 + owb * e1;
      mxv[ct] = nm;
    }
  }

  __syncthreads();  // all waves done reading w3s/h2s -> reuse smem front for attL/part
  if (lg == 0) {
    #pragma unroll
    for (int ct = 0; ct < 4; ++ct) {
      const int c = w * 64 + ct * 16 + lr;
      attL[c] = A[(size_t)n * 256 + c] - wbv[ct] / fmaxf(smv[ct], 1e-30f);
    }
  }
  __syncthreads();

  // ---- fc: out[o] = fcb[o] + sum_c attL[c]*fcw[o][c]; 16 partials per o ----
  {
    const int o = tid >> 4, gp = tid & 15;
    if (o < 13) {
      float s = 0.f;
      #pragma unroll
      for (int i = 0; i < 4; ++i) {
        float4_t av = *(const float4_t*)&attL[gp * 16 + i * 4];
        float4_t wv = *(const float4_t*)&fcw[(size_t)o * 256 + gp * 16 + i * 4];
        #pragma unroll
        for (int e = 0; e < 4; ++e) s = fmaf(av[e], wv[e], s);
      }
      part[o * 16 + gp] = s;
    }
  }
  __syncthreads();
  if (tid < 13) {
    float s = fcb[tid];
    #pragma unroll
    for (int gp = 0; gp < 16; ++gp) s += part[tid * 16 + gp];
    outp[(size_t)n * 13 + tid] = s;
  }
}

extern "C" void kernel_launch(void* const* d_in, const int* in_sizes, int n_in,
                              void* d_out, int out_size, void* d_ws, size_t ws_size,
                              hipStream_t stream)
{
  const float* ext = (const float*)d_in[0];
  const float* lab = (const float*)d_in[1];
  const float* w1a = (const float*)d_in[2];
  const float* b1a = (const float*)d_in[3];
  const float* g1a = (const float*)d_in[4];
  const float* be1a= (const float*)d_in[5];
  const float* w1b = (const float*)d_in[6];
  const float* b1b = (const float*)d_in[7];
  const float* g1b = (const float*)d_in[8];
  const float* be1b= (const float*)d_in[9];
  const float* w2a = (const float*)d_in[10];
  const float* b2a = (const float*)d_in[11];
  const float* g2a = (const float*)d_in[12];
  const float* be2a= (const float*)d_in[13];
  const float* w2b = (const float*)d_in[14];
  const float* b2b = (const float*)d_in[15];
  const float* g2b = (const float*)d_in[16];
  const float* be2b= (const float*)d_in[17];
  const float* mw1 = (const float*)d_in[18];
  const float* mb1 = (const float*)d_in[19];
  const float* mg1 = (const float*)d_in[20];
  const float* mbe1= (const float*)d_in[21];
  const float* mw2 = (const float*)d_in[22];
  const float* mb2 = (const float*)d_in[23];
  const float* mg2 = (const float*)d_in[24];
  const float* mbe2= (const float*)d_in[25];
  const float* mw3 = (const float*)d_in[26];
  const float* mb3 = (const float*)d_in[27];
  const float* mg3 = (const float*)d_in[28];
  const float* mbe3= (const float*)d_in[29];
  const float* fcw = (const float*)d_in[30];
  const float* fcb = (const float*)d_in[31];

  char* ws = (char*)d_ws;
  float* Y1a  = (float*)(ws);                     // 2048x512 f32 (transient)
  float* Aenc = (float*)(ws + (4u << 20));        // 2048x256 f32
  float* Y1b  = (float*)(ws);                     // 128x512 f32 (reuse of dead Y1a)
  float* Benc = (float*)(ws + (256u << 10));      // 128x256 f32
  float* PA2  = (float*)(ws + (384u << 10));      // 2048x32 f32
  float* PB2  = (float*)(ws + (640u << 10));      // 128x32 f32

  gemm_bn_relu<<<dim3(32, 8), 256, 0, stream>>>(ext, w1a, b1a, g1a, be1a, Y1a, 2048, 512, 352);
  gemm_bn_relu<<<dim3(32, 4), 256, 0, stream>>>(Y1a, w1b, b1b, g1b, be1b, Aenc, 2048, 256, 512);
  gemm_bn_relu<<<dim3(2, 8),  256, 0, stream>>>(lab, w2a, b2a, g2a, be2a, Y1b, 128, 512, 352);
  gemm_bn_relu<<<dim3(2, 4),  256, 0, stream>>>(Y1b, w2b, b2b, g2b, be2b, Benc, 128, 256, 512);
  proj32<<<256, 256, 0, stream>>>(Aenc, mw1, mb1, mg1, mbe1, PA2, 1);
  proj32<<<16, 256, 0, stream>>>(Benc, mw1, mb1, mg1, mbe1, PB2, 0);
  main_attn<<<2048, 256, 0, stream>>>(PA2, PB2, Aenc, Benc,
                                      mw2, mb2, mg2, mbe2, mw3, mb3, mg3, mbe3,
                                      fcw, fcb, (float*)d_out);
}

// Round 5
// 139.537 us; speedup vs baseline: 2.1177x; 1.4208x over previous
//
#include <hip/hip_runtime.h>
#include <stdint.h>

// N=2048, M=128, D_IN=352, H1=512, D=256, OUT_C=13.  All device tensors FLOAT32.
// Algebra: diff = A[n]-B[m] affine -> fold SharedMLP conv1 into PA2[n,32]/PB2[m,32];
// softmax over m sums to 1 -> att[n,c] = A[n,c] - sum_m wei[n,m,c]*B[m,c].
// Round 5: MFMA encoders (bf16 weights/activations pre-converted once), main_attn
// reads w2/w3 B-frags straight from global bf16 (no LDS staging), exp2-folded softmax.
//
// ws layout (peak 5.56MB):
//   [0,2M)        Y1ab bf16 2048x512 (enc1 out; dead after enc2) -> then PA2/PB2
//   [0,256K)      PA2 f32 2048x32   (written by proj, after Y1ab dead)
//   [256K,272K)   PB2 f32 128x32
//   [2M,4M)       Aenc f32 2048x256 (first 1.44M doubles as extb bf16 before enc2)
//   [4M,...)      w1ab|w1bb|w2ab|w2bb|mw2b|mw3b|labb|Y1bb|Benc

typedef __attribute__((ext_vector_type(4))) float float4_t;
typedef __attribute__((ext_vector_type(4))) float f32x4;
typedef __attribute__((ext_vector_type(8))) short bf16x8;
typedef __attribute__((ext_vector_type(8))) unsigned short ushort8_t;
typedef unsigned short ushort_t;

__device__ __forceinline__ unsigned short f2b(float f) {
  union { float f; unsigned int i; } v; v.f = f;
  unsigned int x = v.i;
  return (unsigned short)((x + 0x7FFFu + ((x >> 16) & 1u)) >> 16);
}

// ---------- prep: convert 8 f32 arrays -> bf16, one pass, hardcoded segment table ----------
// items are 8-element groups. cum: ext 90112 | lab 95744 | w1a 118272 | w1b 134656 |
// w2a 157184 | w2b 173568 | mw2 173824 | mw3 175872.  grid 687*256 == 175872.
__global__ __launch_bounds__(256) void cvt_bf16(
    const float* __restrict__ s0, const float* __restrict__ s1,
    const float* __restrict__ s2, const float* __restrict__ s3,
    const float* __restrict__ s4, const float* __restrict__ s5,
    const float* __restrict__ s6, const float* __restrict__ s7,
    ushort_t* __restrict__ d0, ushort_t* __restrict__ d1,
    ushort_t* __restrict__ d2, ushort_t* __restrict__ d3,
    ushort_t* __restrict__ d4, ushort_t* __restrict__ d5,
    ushort_t* __restrict__ d6, ushort_t* __restrict__ d7)
{
  int i = blockIdx.x * 256 + threadIdx.x;
  const float* s; ushort_t* d; int j;
  if      (i < 90112)  { s = s0; d = d0; j = i; }
  else if (i < 95744)  { s = s1; d = d1; j = i - 90112; }
  else if (i < 118272) { s = s2; d = d2; j = i - 95744; }
  else if (i < 134656) { s = s3; d = d3; j = i - 118272; }
  else if (i < 157184) { s = s4; d = d4; j = i - 134656; }
  else if (i < 173568) { s = s5; d = d5; j = i - 157184; }
  else if (i < 173824) { s = s6; d = d6; j = i - 173568; }
  else                 { s = s7; d = d7; j = i - 173824; }
  float4_t v0 = *(const float4_t*)&s[(size_t)j * 8];
  float4_t v1 = *(const float4_t*)&s[(size_t)j * 8 + 4];
  ushort8_t u;
  #pragma unroll
  for (int e = 0; e < 4; ++e) { u[e] = f2b(v0[e]); u[4 + e] = f2b(v1[e]); }
  *(ushort8_t*)&d[(size_t)j * 8] = u;
}

// ---------- MFMA encoder: Y = relu(g*(X @ W^T + b) + be), X/W bf16, acc f32 ----------
// 64x64 block tile, 4 waves (wave w = 16-col slice), K-step 32, reg-prefetch staging.
// A/B same path selected by bx (merges the big A-encode and tiny B-encode launches).
template<int OUT_BF16>
__global__ __launch_bounds__(256) void enc_mfma(
    const ushort_t* __restrict__ XA, const ushort_t* __restrict__ WA,
    const float* __restrict__ bA, const float* __restrict__ gA, const float* __restrict__ beA,
    void* __restrict__ YA,
    const ushort_t* __restrict__ XB, const ushort_t* __restrict__ WB,
    const float* __restrict__ bB, const float* __restrict__ gB, const float* __restrict__ beB,
    void* __restrict__ YB,
    int J, int K, int nbxA)
{
  __shared__ ushort_t Xs[64][40];
  __shared__ ushort_t Ws[64][40];
  const int bx = blockIdx.x, by = blockIdx.y;
  const ushort_t* X; const ushort_t* W;
  const float *bb, *gg, *bev; void* Y; int i0;
  if (bx < nbxA) { X = XA; W = WA; bb = bA; gg = gA; bev = beA; Y = YA; i0 = bx * 64; }
  else           { X = XB; W = WB; bb = bB; gg = gB; bev = beB; Y = YB; i0 = (bx - nbxA) * 64; }
  const int j0 = by * 64;
  const int tid = threadIdx.x, w = tid >> 6, lane = tid & 63, lg = lane >> 4, lr = lane & 15;
  const int sr = tid >> 2, sk = (tid & 3) * 8;

  f32x4 acc[4];
  #pragma unroll
  for (int mt = 0; mt < 4; ++mt) acc[mt] = f32x4{0.f, 0.f, 0.f, 0.f};

  ushort8_t xv = *(const ushort8_t*)&X[(size_t)(i0 + sr) * K + sk];
  ushort8_t wv = *(const ushort8_t*)&W[(size_t)(j0 + sr) * K + sk];
  for (int kt = 0; kt < K; kt += 32) {
    __syncthreads();
    *(ushort8_t*)&Xs[sr][sk] = xv;
    *(ushort8_t*)&Ws[sr][sk] = wv;
    __syncthreads();
    if (kt + 32 < K) {
      xv = *(const ushort8_t*)&X[(size_t)(i0 + sr) * K + kt + 32 + sk];
      wv = *(const ushort8_t*)&W[(size_t)(j0 + sr) * K + kt + 32 + sk];
    }
    bf16x8 bfrag = *(const bf16x8*)&Ws[w * 16 + lr][lg * 8];
    #pragma unroll
    for (int mt = 0; mt < 4; ++mt) {
      bf16x8 af = *(const bf16x8*)&Xs[mt * 16 + lr][lg * 8];
      acc[mt] = __builtin_amdgcn_mfma_f32_16x16x32_bf16(af, bfrag, acc[mt], 0, 0, 0);
    }
  }
  const int c = j0 + w * 16 + lr;
  const float g = gg[c], bv = bb[c], ev = bev[c];
  #pragma unroll
  for (int mt = 0; mt < 4; ++mt)
    #pragma unroll
    for (int r = 0; r < 4; ++r) {
      const int row = i0 + mt * 16 + 4 * lg + r;
      float t = fmaxf(g * (acc[mt][r] + bv) + ev, 0.f);
      if (OUT_BF16) ((ushort_t*)Y)[(size_t)row * J + c] = f2b(t);
      else          ((float*)Y)[(size_t)row * J + c] = t;
    }
}

// ---------- proj: P = fold(X @ mw1^T); A-rows (with bias) and B-rows (g only) merged ----------
__global__ __launch_bounds__(256) void proj32(
    const float* __restrict__ Aenc, const float* __restrict__ Benc,
    const float* __restrict__ mw1, const float* __restrict__ mb1,
    const float* __restrict__ mg1, const float* __restrict__ mbe1,
    float* __restrict__ PA2, float* __restrict__ PB2, int nbxA)
{
  const int tid = threadIdx.x, bx = blockIdx.x;
  const float* X; float* P; int n0, wb;
  if (bx < nbxA) { X = Aenc; P = PA2; n0 = bx * 8; wb = 1; }
  else           { X = Benc; P = PB2; n0 = (bx - nbxA) * 8; wb = 0; }
  const int r = tid >> 5, k = tid & 31;
  const int n = n0 + r;
  const float* xp = &X[(size_t)n * 256];
  const float* wp = &mw1[k * 256];
  float s = 0.f;
  #pragma unroll 8
  for (int q = 0; q < 256; q += 4) {
    float4_t xv = *(const float4_t*)&xp[q];
    float4_t wv = *(const float4_t*)&wp[q];
    #pragma unroll
    for (int e = 0; e < 4; ++e) s = fmaf(xv[e], wv[e], s);
  }
  P[(size_t)n * 32 + k] = wb ? (mg1[k] * (s + mb1[k]) + mbe1[k]) : (mg1[k] * s);
}

// ---------- fused main kernel (MFMA): one block per n, 4 waves ----------
// MFMA 16x16x32_bf16: A frag m=lane&15,k=(lane>>4)*8+e; B frag c=lane&15,same k;
// C/D col=lane&15,row=(lane>>4)*4+reg.
// w2/w3 B-frags read directly from global bf16 (L2-hot).  LDS 28KB:
//   [0,10240) h1s[128][40] | [10240,28672) h2s[128][72]
//   after phase2 barrier: [0,1024) attL f32 | [1024,1856) part f32
__global__ __launch_bounds__(256, 4) void main_attn(
    const float* __restrict__ PA2, const float* __restrict__ PB2,
    const float* __restrict__ A, const float* __restrict__ Bm,
    const ushort_t* __restrict__ mw2b, const float* __restrict__ mb2,
    const float* __restrict__ mg2, const float* __restrict__ mbe2,
    const ushort_t* __restrict__ mw3b, const float* __restrict__ mb3,
    const float* __restrict__ mg3, const float* __restrict__ mbe3,
    const float* __restrict__ fcw, const float* __restrict__ fcb,
    float* __restrict__ outp)
{
  __shared__ __align__(16) char smem[28672];
  ushort_t* h1s = (ushort_t*)smem;                   // [128][40]
  ushort_t* h2s = (ushort_t*)(smem + 10240);         // [128][72]
  float* attL = (float*)smem;                        // [256]  (reuses dead h1s)
  float* part = (float*)(smem + 1024);               // [208]

  const int tid = threadIdx.x;
  const int w = tid >> 6, lane = tid & 63, lg = lane >> 4, lr = lane & 15;
  const int n = blockIdx.x;
  const float LOG2E = 1.4426950408889634f;

  // ---- phase0: h1s[m][k] = relu(PA2[n][k] - PB2[m][k]) bf16 ----
  {
    const int m = tid >> 1, half = tid & 1;
    const float* pa = &PA2[(size_t)n * 32 + half * 16];
    const float* pb = &PB2[(size_t)m * 32 + half * 16];
    #pragma unroll
    for (int q = 0; q < 2; ++q) {
      float4_t a0 = *(const float4_t*)&pa[q * 8];
      float4_t a1 = *(const float4_t*)&pa[q * 8 + 4];
      float4_t b0 = *(const float4_t*)&pb[q * 8];
      float4_t b1 = *(const float4_t*)&pb[q * 8 + 4];
      ushort8_t u;
      #pragma unroll
      for (int e = 0; e < 4; ++e) {
        u[e]     = f2b(fmaxf(a0[e] - b0[e], 0.f));
        u[4 + e] = f2b(fmaxf(a1[e] - b1[e], 0.f));
      }
      *(ushort8_t*)&h1s[m * 40 + half * 16 + q * 8] = u;
    }
  }
  __syncthreads();

  // ---- phase1: h2[m][j] = relu(g2*(h1 @ mw2^T + b2) + be2) -> h2s ----
  // wave w owns m in [w*32, w*32+32): 2 m-tiles x 4 j-tiles, K=32
  {
    f32x4 acc1[2][4];
    #pragma unroll
    for (int mt = 0; mt < 2; ++mt)
      #pragma unroll
      for (int jt = 0; jt < 4; ++jt) acc1[mt][jt] = f32x4{0.f, 0.f, 0.f, 0.f};
    bf16x8 a1[2], b1[4];
    #pragma unroll
    for (int mt = 0; mt < 2; ++mt)
      a1[mt] = *(const bf16x8*)&h1s[(w * 32 + mt * 16 + lr) * 40 + lg * 8];
    #pragma unroll
    for (int jt = 0; jt < 4; ++jt)
      b1[jt] = *(const bf16x8*)&mw2b[(jt * 16 + lr) * 32 + lg * 8];
    #pragma unroll
    for (int mt = 0; mt < 2; ++mt)
      #pragma unroll
      for (int jt = 0; jt < 4; ++jt)
        acc1[mt][jt] = __builtin_amdgcn_mfma_f32_16x16x32_bf16(a1[mt], b1[jt], acc1[mt][jt], 0, 0, 0);
    #pragma unroll
    for (int jt = 0; jt < 4; ++jt) {
      const int j = jt * 16 + lr;
      const float g = mg2[j], bv = mb2[j], ev = mbe2[j];
      #pragma unroll
      for (int mt = 0; mt < 2; ++mt)
        #pragma unroll
        for (int r = 0; r < 4; ++r)
          h2s[(w * 32 + mt * 16 + 4 * lg + r) * 72 + jt * 16 + lr] =
              f2b(fmaxf(g * (acc1[mt][jt][r] + bv) + ev, 0.f));
    }
  }
  __syncthreads();

  // ---- phase2 + softmax (ct-pairs to halve acc pressure) ----
  // wave w owns c in [w*64, w*64+64); logits scaled by LOG2E -> exp2f
  float mxv[4], smv[4], wbv[4];
  #pragma unroll
  for (int cp = 0; cp < 2; ++cp) {
    f32x4 acc[8][2];
    #pragma unroll
    for (int mt = 0; mt < 8; ++mt) {
      acc[mt][0] = f32x4{0.f, 0.f, 0.f, 0.f};
      acc[mt][1] = f32x4{0.f, 0.f, 0.f, 0.f};
    }
    #pragma unroll
    for (int ks = 0; ks < 2; ++ks) {
      bf16x8 bfr[2];
      #pragma unroll
      for (int q = 0; q < 2; ++q) {
        const int c = w * 64 + (cp * 2 + q) * 16 + lr;
        bfr[q] = *(const bf16x8*)&mw3b[(size_t)c * 64 + ks * 32 + lg * 8];
      }
      #pragma unroll
      for (int mt = 0; mt < 8; ++mt) {
        bf16x8 af = *(const bf16x8*)&h2s[(mt * 16 + lr) * 72 + ks * 32 + lg * 8];
        acc[mt][0] = __builtin_amdgcn_mfma_f32_16x16x32_bf16(af, bfr[0], acc[mt][0], 0, 0, 0);
        acc[mt][1] = __builtin_amdgcn_mfma_f32_16x16x32_bf16(af, bfr[1], acc[mt][1], 0, 0, 0);
      }
    }
    #pragma unroll
    for (int q = 0; q < 2; ++q) {
      const int ct = cp * 2 + q;
      const int c = w * 64 + ct * 16 + lr;
      const float g = mg3[c], bv = mb3[c], ev = mbe3[c];
      const float gs = g * LOG2E;
      const float cs = (g * bv + ev) * LOG2E;
      float mx = 0.f;
      float l[8][4];
      #pragma unroll
      for (int mt = 0; mt < 8; ++mt)
        #pragma unroll
        for (int r = 0; r < 4; ++r) {
          float t = fmaxf(fmaf(gs, acc[mt][q][r], cs), 0.f);
          l[mt][r] = t;
          mx = fmaxf(mx, t);
        }
      float sm = 0.f, wb = 0.f;
      #pragma unroll
      for (int mt = 0; mt < 8; ++mt)
        #pragma unroll
        for (int r = 0; r < 4; ++r) {
          const int m = mt * 16 + 4 * lg + r;
          float p = exp2f(l[mt][r] - mx);
          float bval = Bm[(size_t)m * 256 + c];
          sm += p;
          wb = fmaf(p, bval, wb);
        }
      mxv[ct] = mx; smv[ct] = sm; wbv[ct] = wb;
    }
  }
  // merge the 4 lane-groups (m-partition) across lane bits 4,5
  #pragma unroll
  for (int st = 16; st <= 32; st <<= 1) {
    #pragma unroll
    for (int ct = 0; ct < 4; ++ct) {
      float omx = __shfl_xor(mxv[ct], st, 64);
      float osm = __shfl_xor(smv[ct], st, 64);
      float owb = __shfl_xor(wbv[ct], st, 64);
      float nm = fmaxf(mxv[ct], omx);
      float e0 = exp2f(mxv[ct] - nm), e1 = exp2f(omx - nm);
      smv[ct] = smv[ct] * e0 + osm * e1;
      wbv[ct] = wbv[ct] * e0 + owb * e1;
      mxv[ct] = nm;
    }
  }

  __syncthreads();  // all h1s/h2s traffic done -> reuse front of smem
  if (lg == 0) {
    #pragma unroll
    for (int ct = 0; ct < 4; ++ct) {
      const int c = w * 64 + ct * 16 + lr;
      attL[c] = A[(size_t)n * 256 + c] - wbv[ct] / fmaxf(smv[ct], 1e-30f);
    }
  }
  __syncthreads();

  // ---- fc: out[o] = fcb[o] + sum_c attL[c]*fcw[o][c]; 16 partials per o ----
  {
    const int o = tid >> 4, gp = tid & 15;
    if (o < 13) {
      float s = 0.f;
      #pragma unroll
      for (int i = 0; i < 4; ++i) {
        float4_t av = *(const float4_t*)&attL[gp * 16 + i * 4];
        float4_t wv = *(const float4_t*)&fcw[(size_t)o * 256 + gp * 16 + i * 4];
        #pragma unroll
        for (int e = 0; e < 4; ++e) s = fmaf(av[e], wv[e], s);
      }
      part[o * 16 + gp] = s;
    }
  }
  __syncthreads();
  if (tid < 13) {
    float s = fcb[tid];
    #pragma unroll
    for (int gp = 0; gp < 16; ++gp) s += part[tid * 16 + gp];
    outp[(size_t)n * 13 + tid] = s;
  }
}

extern "C" void kernel_launch(void* const* d_in, const int* in_sizes, int n_in,
                              void* d_out, int out_size, void* d_ws, size_t ws_size,
                              hipStream_t stream)
{
  const float* ext = (const float*)d_in[0];
  const float* lab = (const float*)d_in[1];
  const float* w1a = (const float*)d_in[2];
  const float* b1a = (const float*)d_in[3];
  const float* g1a = (const float*)d_in[4];
  const float* be1a= (const float*)d_in[5];
  const float* w1b = (const float*)d_in[6];
  const float* b1b = (const float*)d_in[7];
  const float* g1b = (const float*)d_in[8];
  const float* be1b= (const float*)d_in[9];
  const float* w2a = (const float*)d_in[10];
  const float* b2a = (const float*)d_in[11];
  const float* g2a = (const float*)d_in[12];
  const float* be2a= (const float*)d_in[13];
  const float* w2b = (const float*)d_in[14];
  const float* b2b = (const float*)d_in[15];
  const float* g2b = (const float*)d_in[16];
  const float* be2b= (const float*)d_in[17];
  const float* mw1 = (const float*)d_in[18];
  const float* mb1 = (const float*)d_in[19];
  const float* mg1 = (const float*)d_in[20];
  const float* mbe1= (const float*)d_in[21];
  const float* mw2 = (const float*)d_in[22];
  const float* mb2 = (const float*)d_in[23];
  const float* mg2 = (const float*)d_in[24];
  const float* mbe2= (const float*)d_in[25];
  const float* mw3 = (const float*)d_in[26];
  const float* mb3 = (const float*)d_in[27];
  const float* mg3 = (const float*)d_in[28];
  const float* mbe3= (const float*)d_in[29];
  const float* fcw = (const float*)d_in[30];
  const float* fcb = (const float*)d_in[31];

  char* ws = (char*)d_ws;
  ushort_t* Y1ab = (ushort_t*)(ws);                       // [0,2M) bf16 2048x512
  float*    PA2  = (float*)(ws);                          // [0,256K) after Y1ab dead
  float*    PB2  = (float*)(ws + 262144);                 // [256K,272K)
  float*    Aenc = (float*)(ws + (2u << 20));             // [2M,4M) f32 2048x256
  ushort_t* extb = (ushort_t*)(ws + (2u << 20));          // alias (dead before Aenc write)
  char* b5 = ws + (4u << 20);
  ushort_t* w1ab = (ushort_t*)(b5);                       // 512x352
  ushort_t* w1bb = (ushort_t*)(b5 + 360448);              // 256x512
  ushort_t* w2ab = (ushort_t*)(b5 + 622592);              // 512x352
  ushort_t* w2bb = (ushort_t*)(b5 + 983040);              // 256x512
  ushort_t* mw2b = (ushort_t*)(b5 + 1245184);             // 64x32
  ushort_t* mw3b = (ushort_t*)(b5 + 1249280);             // 256x64
  ushort_t* labb = (ushort_t*)(b5 + 1282048);             // 128x352
  ushort_t* Y1bb = (ushort_t*)(b5 + 1372160);             // 128x512 bf16
  float*    Benc = (float*)(b5 + 1503232);                // 128x256 f32

  cvt_bf16<<<687, 256, 0, stream>>>(ext, lab, w1a, w1b, w2a, w2b, mw2, mw3,
                                    extb, labb, w1ab, w1bb, w2ab, w2bb, mw2b, mw3b);
  enc_mfma<1><<<dim3(34, 8), 256, 0, stream>>>(
      extb, w1ab, b1a, g1a, be1a, (void*)Y1ab,
      labb, w2ab, b2a, g2a, be2a, (void*)Y1bb, 512, 352, 32);
  enc_mfma<0><<<dim3(34, 4), 256, 0, stream>>>(
      Y1ab, w1bb, b1b, g1b, be1b, (void*)Aenc,
      Y1bb, w2bb, b2b, g2b, be2b, (void*)Benc, 256, 512, 32);
  proj32<<<272, 256, 0, stream>>>(Aenc, Benc, mw1, mb1, mg1, mbe1, PA2, PB2, 256);
  main_attn<<<2048, 256, 0, stream>>>(PA2, PB2, Aenc, Benc,
                                      mw2b, mb2, mg2, mbe2, mw3b, mb3, mg3, mbe3,
                                      fcw, fcb, (float*)d_out);
}

// Round 6
// 99.826 us; speedup vs baseline: 2.9601x; 1.3978x over previous
//
#include <hip/hip_runtime.h>
#include <stdint.h>

// N=2048, M=128, D_IN=352, H1=512, D=256, OUT_C=13.  All device tensors FLOAT32.
// Algebra: diff = A[n]-B[m] affine -> fold SharedMLP conv1 into PA2[n,32]/PB2[m,32];
// softmax over m sums to 1 -> att[n,c] = A[n,c] - sum_m wei[n,m,c]*B[m,c].
// Round 6: fix R5 spill regression (launch_bounds(256,2); logits in-place in acc)
// + BencT transposed copy so the softmax B-pass uses float4 loads.

typedef __attribute__((ext_vector_type(4))) float float4_t;
typedef __attribute__((ext_vector_type(4))) float f32x4;
typedef __attribute__((ext_vector_type(8))) short bf16x8;
typedef __attribute__((ext_vector_type(8))) unsigned short ushort8_t;
typedef unsigned short ushort_t;

__device__ __forceinline__ unsigned short f2b(float f) {
  union { float f; unsigned int i; } v; v.f = f;
  unsigned int x = v.i;
  return (unsigned short)((x + 0x7FFFu + ((x >> 16) & 1u)) >> 16);
}

// ---------- prep: convert 8 f32 arrays -> bf16, one pass ----------
// 8-elem groups, cum: ext 90112 | lab 95744 | w1a 118272 | w1b 134656 |
// w2a 157184 | w2b 173568 | mw2 173824 | mw3 175872.  grid 687*256 == 175872.
__global__ __launch_bounds__(256) void cvt_bf16(
    const float* __restrict__ s0, const float* __restrict__ s1,
    const float* __restrict__ s2, const float* __restrict__ s3,
    const float* __restrict__ s4, const float* __restrict__ s5,
    const float* __restrict__ s6, const float* __restrict__ s7,
    ushort_t* __restrict__ d0, ushort_t* __restrict__ d1,
    ushort_t* __restrict__ d2, ushort_t* __restrict__ d3,
    ushort_t* __restrict__ d4, ushort_t* __restrict__ d5,
    ushort_t* __restrict__ d6, ushort_t* __restrict__ d7)
{
  int i = blockIdx.x * 256 + threadIdx.x;
  const float* s; ushort_t* d; int j;
  if      (i < 90112)  { s = s0; d = d0; j = i; }
  else if (i < 95744)  { s = s1; d = d1; j = i - 90112; }
  else if (i < 118272) { s = s2; d = d2; j = i - 95744; }
  else if (i < 134656) { s = s3; d = d3; j = i - 118272; }
  else if (i < 157184) { s = s4; d = d4; j = i - 134656; }
  else if (i < 173568) { s = s5; d = d5; j = i - 157184; }
  else if (i < 173824) { s = s6; d = d6; j = i - 173568; }
  else                 { s = s7; d = d7; j = i - 173824; }
  float4_t v0 = *(const float4_t*)&s[(size_t)j * 8];
  float4_t v1 = *(const float4_t*)&s[(size_t)j * 8 + 4];
  ushort8_t u;
  #pragma unroll
  for (int e = 0; e < 4; ++e) { u[e] = f2b(v0[e]); u[4 + e] = f2b(v1[e]); }
  *(ushort8_t*)&d[(size_t)j * 8] = u;
}

// ---------- MFMA encoder: Y = relu(g*(X @ W^T + b) + be), X/W bf16, acc f32 ----------
// 64x64 tile, 4 waves (wave w = 16-col slice), K-step 32, reg-prefetch staging.
// A and B encodes merged via bx; B-branch (bx>=nbxA) optionally also stores
// the transposed f32 output YT[c*128+row] (only used by the last encoder stage).
template<int OUT_BF16>
__global__ __launch_bounds__(256) void enc_mfma(
    const ushort_t* __restrict__ XA, const ushort_t* __restrict__ WA,
    const float* __restrict__ bA, const float* __restrict__ gA, const float* __restrict__ beA,
    void* __restrict__ YA,
    const ushort_t* __restrict__ XB, const ushort_t* __restrict__ WB,
    const float* __restrict__ bB, const float* __restrict__ gB, const float* __restrict__ beB,
    void* __restrict__ YB, float* __restrict__ YBT,
    int J, int K, int nbxA)
{
  __shared__ ushort_t Xs[64][40];
  __shared__ ushort_t Ws[64][40];
  const int bx = blockIdx.x, by = blockIdx.y;
  const ushort_t* X; const ushort_t* W;
  const float *bb, *gg, *bev; void* Y; int i0, isB;
  if (bx < nbxA) { X = XA; W = WA; bb = bA; gg = gA; bev = beA; Y = YA; i0 = bx * 64; isB = 0; }
  else           { X = XB; W = WB; bb = bB; gg = gB; bev = beB; Y = YB; i0 = (bx - nbxA) * 64; isB = 1; }
  const int j0 = by * 64;
  const int tid = threadIdx.x, w = tid >> 6, lane = tid & 63, lg = lane >> 4, lr = lane & 15;
  const int sr = tid >> 2, sk = (tid & 3) * 8;

  f32x4 acc[4];
  #pragma unroll
  for (int mt = 0; mt < 4; ++mt) acc[mt] = f32x4{0.f, 0.f, 0.f, 0.f};

  ushort8_t xv = *(const ushort8_t*)&X[(size_t)(i0 + sr) * K + sk];
  ushort8_t wv = *(const ushort8_t*)&W[(size_t)(j0 + sr) * K + sk];
  for (int kt = 0; kt < K; kt += 32) {
    __syncthreads();
    *(ushort8_t*)&Xs[sr][sk] = xv;
    *(ushort8_t*)&Ws[sr][sk] = wv;
    __syncthreads();
    if (kt + 32 < K) {
      xv = *(const ushort8_t*)&X[(size_t)(i0 + sr) * K + kt + 32 + sk];
      wv = *(const ushort8_t*)&W[(size_t)(j0 + sr) * K + kt + 32 + sk];
    }
    bf16x8 bfrag = *(const bf16x8*)&Ws[w * 16 + lr][lg * 8];
    #pragma unroll
    for (int mt = 0; mt < 4; ++mt) {
      bf16x8 af = *(const bf16x8*)&Xs[mt * 16 + lr][lg * 8];
      acc[mt] = __builtin_amdgcn_mfma_f32_16x16x32_bf16(af, bfrag, acc[mt], 0, 0, 0);
    }
  }
  const int c = j0 + w * 16 + lr;
  const float g = gg[c], bv = bb[c], ev = bev[c];
  #pragma unroll
  for (int mt = 0; mt < 4; ++mt)
    #pragma unroll
    for (int r = 0; r < 4; ++r) {
      const int row = i0 + mt * 16 + 4 * lg + r;
      float t = fmaxf(g * (acc[mt][r] + bv) + ev, 0.f);
      if (OUT_BF16) ((ushort_t*)Y)[(size_t)row * J + c] = f2b(t);
      else {
        ((float*)Y)[(size_t)row * J + c] = t;
        if (isB && YBT) YBT[(size_t)c * 128 + row] = t;
      }
    }
}

// ---------- proj: P = fold(X @ mw1^T); A-rows (bias) and B-rows (g only) merged ----------
__global__ __launch_bounds__(256) void proj32(
    const float* __restrict__ Aenc, const float* __restrict__ Benc,
    const float* __restrict__ mw1, const float* __restrict__ mb1,
    const float* __restrict__ mg1, const float* __restrict__ mbe1,
    float* __restrict__ PA2, float* __restrict__ PB2, int nbxA)
{
  const int tid = threadIdx.x, bx = blockIdx.x;
  const float* X; float* P; int n0, wb;
  if (bx < nbxA) { X = Aenc; P = PA2; n0 = bx * 8; wb = 1; }
  else           { X = Benc; P = PB2; n0 = (bx - nbxA) * 8; wb = 0; }
  const int r = tid >> 5, k = tid & 31;
  const int n = n0 + r;
  const float* xp = &X[(size_t)n * 256];
  const float* wp = &mw1[k * 256];
  float s = 0.f;
  #pragma unroll 8
  for (int q = 0; q < 256; q += 4) {
    float4_t xv = *(const float4_t*)&xp[q];
    float4_t wv = *(const float4_t*)&wp[q];
    #pragma unroll
    for (int e = 0; e < 4; ++e) s = fmaf(xv[e], wv[e], s);
  }
  P[(size_t)n * 32 + k] = wb ? (mg1[k] * (s + mb1[k]) + mbe1[k]) : (mg1[k] * s);
}

// ---------- fused main kernel (MFMA): one block per n, 4 waves ----------
// MFMA 16x16x32_bf16: A frag m=lane&15,k=(lane>>4)*8+e; B frag c=lane&15,same k;
// C/D col=lane&15,row=(lane>>4)*4+reg.
// w2/w3 B-frags read directly from global bf16 (L2-hot).  LDS 28KB:
//   [0,10240) h1s[128][40] | [10240,28672) h2s[128][72]
//   after phase2 barrier: [0,1024) attL f32 | [1024,1856) part f32
__global__ __launch_bounds__(256, 2) void main_attn(
    const float* __restrict__ PA2, const float* __restrict__ PB2,
    const float* __restrict__ A, const float* __restrict__ BmT,
    const ushort_t* __restrict__ mw2b, const float* __restrict__ mb2,
    const float* __restrict__ mg2, const float* __restrict__ mbe2,
    const ushort_t* __restrict__ mw3b, const float* __restrict__ mb3,
    const float* __restrict__ mg3, const float* __restrict__ mbe3,
    const float* __restrict__ fcw, const float* __restrict__ fcb,
    float* __restrict__ outp)
{
  __shared__ __align__(16) char smem[28672];
  ushort_t* h1s = (ushort_t*)smem;                   // [128][40]
  ushort_t* h2s = (ushort_t*)(smem + 10240);         // [128][72]
  float* attL = (float*)smem;                        // [256]  (reuses dead h1s)
  float* part = (float*)(smem + 1024);               // [208]

  const int tid = threadIdx.x;
  const int w = tid >> 6, lane = tid & 63, lg = lane >> 4, lr = lane & 15;
  const int n = blockIdx.x;
  const float LOG2E = 1.4426950408889634f;

  // ---- phase0: h1s[m][k] = relu(PA2[n][k] - PB2[m][k]) bf16 ----
  {
    const int m = tid >> 1, half = tid & 1;
    const float* pa = &PA2[(size_t)n * 32 + half * 16];
    const float* pb = &PB2[(size_t)m * 32 + half * 16];
    #pragma unroll
    for (int q = 0; q < 2; ++q) {
      float4_t a0 = *(const float4_t*)&pa[q * 8];
      float4_t a1 = *(const float4_t*)&pa[q * 8 + 4];
      float4_t b0 = *(const float4_t*)&pb[q * 8];
      float4_t b1 = *(const float4_t*)&pb[q * 8 + 4];
      ushort8_t u;
      #pragma unroll
      for (int e = 0; e < 4; ++e) {
        u[e]     = f2b(fmaxf(a0[e] - b0[e], 0.f));
        u[4 + e] = f2b(fmaxf(a1[e] - b1[e], 0.f));
      }
      *(ushort8_t*)&h1s[m * 40 + half * 16 + q * 8] = u;
    }
  }
  __syncthreads();

  // ---- phase1: h2[m][j] = relu(g2*(h1 @ mw2^T + b2) + be2) -> h2s ----
  {
    f32x4 acc1[2][4];
    #pragma unroll
    for (int mt = 0; mt < 2; ++mt)
      #pragma unroll
      for (int jt = 0; jt < 4; ++jt) acc1[mt][jt] = f32x4{0.f, 0.f, 0.f, 0.f};
    bf16x8 a1[2], b1[4];
    #pragma unroll
    for (int mt = 0; mt < 2; ++mt)
      a1[mt] = *(const bf16x8*)&h1s[(w * 32 + mt * 16 + lr) * 40 + lg * 8];
    #pragma unroll
    for (int jt = 0; jt < 4; ++jt)
      b1[jt] = *(const bf16x8*)&mw2b[(jt * 16 + lr) * 32 + lg * 8];
    #pragma unroll
    for (int mt = 0; mt < 2; ++mt)
      #pragma unroll
      for (int jt = 0; jt < 4; ++jt)
        acc1[mt][jt] = __builtin_amdgcn_mfma_f32_16x16x32_bf16(a1[mt], b1[jt], acc1[mt][jt], 0, 0, 0);
    #pragma unroll
    for (int jt = 0; jt < 4; ++jt) {
      const int j = jt * 16 + lr;
      const float g = mg2[j], bv = mb2[j], ev = mbe2[j];
      #pragma unroll
      for (int mt = 0; mt < 2; ++mt)
        #pragma unroll
        for (int r = 0; r < 4; ++r)
          h2s[(w * 32 + mt * 16 + 4 * lg + r) * 72 + jt * 16 + lr] =
              f2b(fmaxf(g * (acc1[mt][jt][r] + bv) + ev, 0.f));
    }
  }
  __syncthreads();

  // ---- phase2 + softmax, ct-pairs; logits written in-place into acc ----
  float mxv[4], smv[4], wbv[4];
  #pragma unroll
  for (int cp = 0; cp < 2; ++cp) {
    f32x4 acc[8][2];
    #pragma unroll
    for (int mt = 0; mt < 8; ++mt) {
      acc[mt][0] = f32x4{0.f, 0.f, 0.f, 0.f};
      acc[mt][1] = f32x4{0.f, 0.f, 0.f, 0.f};
    }
    #pragma unroll
    for (int ks = 0; ks < 2; ++ks) {
      bf16x8 bfr[2];
      #pragma unroll
      for (int q = 0; q < 2; ++q) {
        const int c = w * 64 + (cp * 2 + q) * 16 + lr;
        bfr[q] = *(const bf16x8*)&mw3b[(size_t)c * 64 + ks * 32 + lg * 8];
      }
      #pragma unroll
      for (int mt = 0; mt < 8; ++mt) {
        bf16x8 af = *(const bf16x8*)&h2s[(mt * 16 + lr) * 72 + ks * 32 + lg * 8];
        acc[mt][0] = __builtin_amdgcn_mfma_f32_16x16x32_bf16(af, bfr[0], acc[mt][0], 0, 0, 0);
        acc[mt][1] = __builtin_amdgcn_mfma_f32_16x16x32_bf16(af, bfr[1], acc[mt][1], 0, 0, 0);
      }
    }
    #pragma unroll
    for (int q = 0; q < 2; ++q) {
      const int ct = cp * 2 + q;
      const int c = w * 64 + ct * 16 + lr;
      const float g = mg3[c], bv = mb3[c], ev = mbe3[c];
      const float gs = g * LOG2E;
      const float cs = (g * bv + ev) * LOG2E;
      float mx = 0.f;
      #pragma unroll
      for (int mt = 0; mt < 8; ++mt)
        #pragma unroll
        for (int r = 0; r < 4; ++r) {
          float t = fmaxf(fmaf(gs, acc[mt][q][r], cs), 0.f);
          acc[mt][q][r] = t;             // logit in place (base-2 scaled)
          mx = fmaxf(mx, t);
        }
      float sm = 0.f, wb = 0.f;
      #pragma unroll
      for (int mt = 0; mt < 8; ++mt) {
        float4_t bv4 = *(const float4_t*)&BmT[(size_t)c * 128 + mt * 16 + 4 * lg];
        #pragma unroll
        for (int r = 0; r < 4; ++r) {
          float p = exp2f(acc[mt][q][r] - mx);
          sm += p;
          wb = fmaf(p, bv4[r], wb);
        }
      }
      mxv[ct] = mx; smv[ct] = sm; wbv[ct] = wb;
    }
  }
  // merge the 4 lane-groups (m-partition) across lane bits 4,5
  #pragma unroll
  for (int st = 16; st <= 32; st <<= 1) {
    #pragma unroll
    for (int ct = 0; ct < 4; ++ct) {
      float omx = __shfl_xor(mxv[ct], st, 64);
      float osm = __shfl_xor(smv[ct], st, 64);
      float owb = __shfl_xor(wbv[ct], st, 64);
      float nm = fmaxf(mxv[ct], omx);
      float e0 = exp2f(mxv[ct] - nm), e1 = exp2f(omx - nm);
      smv[ct] = smv[ct] * e0 + osm * e1;
      wbv[ct] = wbv[ct] * e0 + owb * e1;
      mxv[ct] = nm;
    }
  }

  __syncthreads();  // all h1s/h2s traffic done -> reuse front of smem
  if (lg == 0) {
    #pragma unroll
    for (int ct = 0; ct < 4; ++ct) {
      const int c = w * 64 + ct * 16 + lr;
      attL[c] = A[(size_t)n * 256 + c] - wbv[ct] / fmaxf(smv[ct], 1e-30f);
    }
  }
  __syncthreads();

  // ---- fc: out[o] = fcb[o] + sum_c attL[c]*fcw[o][c]; 16 partials per o ----
  {
    const int o = tid >> 4, gp = tid & 15;
    if (o < 13) {
      float s = 0.f;
      #pragma unroll
      for (int i = 0; i < 4; ++i) {
        float4_t av = *(const float4_t*)&attL[gp * 16 + i * 4];
        float4_t wv = *(const float4_t*)&fcw[(size_t)o * 256 + gp * 16 + i * 4];
        #pragma unroll
        for (int e = 0; e < 4; ++e) s = fmaf(av[e], wv[e], s);
      }
      part[o * 16 + gp] = s;
    }
  }
  __syncthreads();
  if (tid < 13) {
    float s = fcb[tid];
    #pragma unroll
    for (int gp = 0; gp < 16; ++gp) s += part[tid * 16 + gp];
    outp[(size_t)n * 13 + tid] = s;
  }
}

extern "C" void kernel_launch(void* const* d_in, const int* in_sizes, int n_in,
                              void* d_out, int out_size, void* d_ws, size_t ws_size,
                              hipStream_t stream)
{
  const float* ext = (const float*)d_in[0];
  const float* lab = (const float*)d_in[1];
  const float* w1a = (const float*)d_in[2];
  const float* b1a = (const float*)d_in[3];
  const float* g1a = (const float*)d_in[4];
  const float* be1a= (const float*)d_in[5];
  const float* w1b = (const float*)d_in[6];
  const float* b1b = (const float*)d_in[7];
  const float* g1b = (const float*)d_in[8];
  const float* be1b= (const float*)d_in[9];
  const float* w2a = (const float*)d_in[10];
  const float* b2a = (const float*)d_in[11];
  const float* g2a = (const float*)d_in[12];
  const float* be2a= (const float*)d_in[13];
  const float* w2b = (const float*)d_in[14];
  const float* b2b = (const float*)d_in[15];
  const float* g2b = (const float*)d_in[16];
  const float* be2b= (const float*)d_in[17];
  const float* mw1 = (const float*)d_in[18];
  const float* mb1 = (const float*)d_in[19];
  const float* mg1 = (const float*)d_in[20];
  const float* mbe1= (const float*)d_in[21];
  const float* mw2 = (const float*)d_in[22];
  const float* mb2 = (const float*)d_in[23];
  const float* mg2 = (const float*)d_in[24];
  const float* mbe2= (const float*)d_in[25];
  const float* mw3 = (const float*)d_in[26];
  const float* mb3 = (const float*)d_in[27];
  const float* mg3 = (const float*)d_in[28];
  const float* mbe3= (const float*)d_in[29];
  const float* fcw = (const float*)d_in[30];
  const float* fcb = (const float*)d_in[31];

  char* ws = (char*)d_ws;
  ushort_t* Y1ab = (ushort_t*)(ws);                       // [0,2M) bf16 2048x512
  float*    PA2  = (float*)(ws);                          // [0,256K) after Y1ab dead
  float*    PB2  = (float*)(ws + 262144);                 // [256K,272K)
  float*    Aenc = (float*)(ws + (2u << 20));             // [2M,4M) f32 2048x256
  ushort_t* extb = (ushort_t*)(ws + (2u << 20));          // alias (dead before Aenc write)
  char* b5 = ws + (4u << 20);
  ushort_t* w1ab = (ushort_t*)(b5);                       // 512x352
  ushort_t* w1bb = (ushort_t*)(b5 + 360448);              // 256x512
  ushort_t* w2ab = (ushort_t*)(b5 + 622592);              // 512x352
  ushort_t* w2bb = (ushort_t*)(b5 + 983040);              // 256x512
  ushort_t* mw2b = (ushort_t*)(b5 + 1245184);             // 64x32
  ushort_t* mw3b = (ushort_t*)(b5 + 1249280);             // 256x64
  ushort_t* labb = (ushort_t*)(b5 + 1282048);             // 128x352
  ushort_t* Y1bb = (ushort_t*)(b5 + 1372160);             // 128x512 bf16
  float*    Benc = (float*)(b5 + 1503232);                // 128x256 f32
  float*    BencT= (float*)(b5 + 1634304);                // 256x128 f32 (transposed)

  cvt_bf16<<<687, 256, 0, stream>>>(ext, lab, w1a, w1b, w2a, w2b, mw2, mw3,
                                    extb, labb, w1ab, w1bb, w2ab, w2bb, mw2b, mw3b);
  enc_mfma<1><<<dim3(34, 8), 256, 0, stream>>>(
      extb, w1ab, b1a, g1a, be1a, (void*)Y1ab,
      labb, w2ab, b2a, g2a, be2a, (void*)Y1bb, (float*)nullptr, 512, 352, 32);
  enc_mfma<0><<<dim3(34, 4), 256, 0, stream>>>(
      Y1ab, w1bb, b1b, g1b, be1b, (void*)Aenc,
      Y1bb, w2bb, b2b, g2b, be2b, (void*)Benc, BencT, 256, 512, 32);
  proj32<<<272, 256, 0, stream>>>(Aenc, Benc, mw1, mb1, mg1, mbe1, PA2, PB2, 256);
  main_attn<<<2048, 256, 0, stream>>>(PA2, PB2, Aenc, BencT,
                                      mw2b, mb2, mg2, mbe2, mw3b, mb3, mg3, mbe3,
                                      fcw, fcb, (float*)d_out);
}

// Round 7
// 98.900 us; speedup vs baseline: 2.9878x; 1.0094x over previous
//
#include <hip/hip_runtime.h>
#include <stdint.h>

// N=2048, M=128, D_IN=352, H1=512, D=256, OUT_C=13.  All device tensors FLOAT32.
// Algebra: diff = A[n]-B[m] affine -> fold SharedMLP conv1 into PA2[n,32]/PB2[m,32];
// softmax over m sums to 1 -> att[n,c] = A[n,c] - sum_m wei[n,m,c]*B[m,c].
// Round 7: no-max single-pass softmax (relu'd logits -> exp2(med3(l,0,80)), exact);
// h1s/phase0 removed (phase1 frags from PA2/PB2 direct); cvt kernel folded into
// encoder staging + proj32 spare blocks.  4 kernels total.

typedef __attribute__((ext_vector_type(4))) float float4_t;
typedef __attribute__((ext_vector_type(4))) float f32x4;
typedef __attribute__((ext_vector_type(8))) short bf16x8;
typedef __attribute__((ext_vector_type(8))) unsigned short ushort8_t;
typedef unsigned short ushort_t;

__device__ __forceinline__ unsigned short f2b(float f) {
  union { float f; unsigned int i; } v; v.f = f;
  unsigned int x = v.i;
  return (unsigned short)((x + 0x7FFFu + ((x >> 16) & 1u)) >> 16);
}

// load 8 contiguous elements as bf16x8-equivalent, converting if source is f32
template<int ISBF>
__device__ __forceinline__ ushort8_t ld8(const void* base, size_t idx) {
  if constexpr (ISBF) {
    return *(const ushort8_t*)((const ushort_t*)base + idx);
  } else {
    const float* p = (const float*)base + idx;
    float4_t v0 = *(const float4_t*)p;
    float4_t v1 = *(const float4_t*)(p + 4);
    ushort8_t u;
    #pragma unroll
    for (int e = 0; e < 4; ++e) { u[e] = f2b(v0[e]); u[4 + e] = f2b(v1[e]); }
    return u;
  }
}

// ---------- MFMA encoder: Y = relu(g*(X @ W^T + b) + be) ----------
// 64x64 tile, 4 waves, K-step 32, reg-prefetch staging; converts f32 operands to
// bf16 during staging (XBF/WBF select).  A and B problems merged via bx.
// B-branch of the f32-out stage also writes the transposed copy YBT[c*128+row].
template<int XBF, int WBF, int OUT_BF16>
__global__ __launch_bounds__(256) void enc_mfma(
    const void* __restrict__ XA, const void* __restrict__ WA,
    const float* __restrict__ bA, const float* __restrict__ gA, const float* __restrict__ beA,
    void* __restrict__ YA,
    const void* __restrict__ XB, const void* __restrict__ WB,
    const float* __restrict__ bB, const float* __restrict__ gB, const float* __restrict__ beB,
    void* __restrict__ YB, float* __restrict__ YBT,
    int J, int K, int nbxA)
{
  __shared__ ushort_t Xs[64][40];
  __shared__ ushort_t Ws[64][40];
  const int bx = blockIdx.x, by = blockIdx.y;
  const void* X; const void* W;
  const float *bb, *gg, *bev; void* Y; int i0, isB;
  if (bx < nbxA) { X = XA; W = WA; bb = bA; gg = gA; bev = beA; Y = YA; i0 = bx * 64; isB = 0; }
  else           { X = XB; W = WB; bb = bB; gg = gB; bev = beB; Y = YB; i0 = (bx - nbxA) * 64; isB = 1; }
  const int j0 = by * 64;
  const int tid = threadIdx.x, w = tid >> 6, lane = tid & 63, lg = lane >> 4, lr = lane & 15;
  const int sr = tid >> 2, sk = (tid & 3) * 8;

  f32x4 acc[4];
  #pragma unroll
  for (int mt = 0; mt < 4; ++mt) acc[mt] = f32x4{0.f, 0.f, 0.f, 0.f};

  ushort8_t xv = ld8<XBF>(X, (size_t)(i0 + sr) * K + sk);
  ushort8_t wv = ld8<WBF>(W, (size_t)(j0 + sr) * K + sk);
  for (int kt = 0; kt < K; kt += 32) {
    __syncthreads();
    *(ushort8_t*)&Xs[sr][sk] = xv;
    *(ushort8_t*)&Ws[sr][sk] = wv;
    __syncthreads();
    if (kt + 32 < K) {
      xv = ld8<XBF>(X, (size_t)(i0 + sr) * K + kt + 32 + sk);
      wv = ld8<WBF>(W, (size_t)(j0 + sr) * K + kt + 32 + sk);
    }
    bf16x8 bfrag = *(const bf16x8*)&Ws[w * 16 + lr][lg * 8];
    #pragma unroll
    for (int mt = 0; mt < 4; ++mt) {
      bf16x8 af = *(const bf16x8*)&Xs[mt * 16 + lr][lg * 8];
      acc[mt] = __builtin_amdgcn_mfma_f32_16x16x32_bf16(af, bfrag, acc[mt], 0, 0, 0);
    }
  }
  const int c = j0 + w * 16 + lr;
  const float g = gg[c], bv = bb[c], ev = bev[c];
  #pragma unroll
  for (int mt = 0; mt < 4; ++mt)
    #pragma unroll
    for (int r = 0; r < 4; ++r) {
      const int row = i0 + mt * 16 + 4 * lg + r;
      float t = fmaxf(g * (acc[mt][r] + bv) + ev, 0.f);
      if (OUT_BF16) ((ushort_t*)Y)[(size_t)row * J + c] = f2b(t);
      else {
        ((float*)Y)[(size_t)row * J + c] = t;
        if (isB && YBT) YBT[(size_t)c * 128 + row] = t;
      }
    }
}

// ---------- proj: P = fold(X @ mw1^T); plus 9 spare blocks convert mw2/mw3 -> bf16 ----------
__global__ __launch_bounds__(256) void proj32(
    const float* __restrict__ Aenc, const float* __restrict__ Benc,
    const float* __restrict__ mw1, const float* __restrict__ mb1,
    const float* __restrict__ mg1, const float* __restrict__ mbe1,
    float* __restrict__ PA2, float* __restrict__ PB2, int nbxA,
    const float* __restrict__ mw2, const float* __restrict__ mw3,
    ushort_t* __restrict__ mw2b, ushort_t* __restrict__ mw3b)
{
  const int tid = threadIdx.x, bx = blockIdx.x;
  if (bx >= nbxA + 16) {
    // conversion blocks: 2304 groups of 8 (mw2: 256 groups, mw3: 2048 groups)
    const int g = (bx - nbxA - 16) * 256 + tid;
    const float* s; ushort_t* d; int j;
    if (g < 256) { s = mw2; d = mw2b; j = g; }
    else         { s = mw3; d = mw3b; j = g - 256; }
    float4_t v0 = *(const float4_t*)&s[(size_t)j * 8];
    float4_t v1 = *(const float4_t*)&s[(size_t)j * 8 + 4];
    ushort8_t u;
    #pragma unroll
    for (int e = 0; e < 4; ++e) { u[e] = f2b(v0[e]); u[4 + e] = f2b(v1[e]); }
    *(ushort8_t*)&d[(size_t)j * 8] = u;
    return;
  }
  const float* X; float* P; int n0, wb;
  if (bx < nbxA) { X = Aenc; P = PA2; n0 = bx * 8; wb = 1; }
  else           { X = Benc; P = PB2; n0 = (bx - nbxA) * 8; wb = 0; }
  const int r = tid >> 5, k = tid & 31;
  const int n = n0 + r;
  const float* xp = &X[(size_t)n * 256];
  const float* wp = &mw1[k * 256];
  float s = 0.f;
  #pragma unroll 8
  for (int q = 0; q < 256; q += 4) {
    float4_t xv = *(const float4_t*)&xp[q];
    float4_t wv = *(const float4_t*)&wp[q];
    #pragma unroll
    for (int e = 0; e < 4; ++e) s = fmaf(xv[e], wv[e], s);
  }
  P[(size_t)n * 32 + k] = wb ? (mg1[k] * (s + mb1[k]) + mbe1[k]) : (mg1[k] * s);
}

// ---------- fused main kernel (MFMA): one block per n, 4 waves ----------
// MFMA 16x16x32_bf16: A frag m=lane&15,k=(lane>>4)*8+e; B frag c=lane&15,same k;
// C/D col=lane&15,row=(lane>>4)*4+reg.
// Softmax: logits relu'd >= 0; shift-invariance -> NO max pass: p = exp2(med3(l,0,80)).
// LDS 18.5KB: [0,18432) h2s[128][72] bf16; after phase2 barrier the same region is
// reused: [0,1024) attL f32 | [1024,1856) part f32.
__global__ __launch_bounds__(256, 2) void main_attn(
    const float* __restrict__ PA2, const float* __restrict__ PB2,
    const float* __restrict__ A, const float* __restrict__ BmT,
    const ushort_t* __restrict__ mw2b, const float* __restrict__ mb2,
    const float* __restrict__ mg2, const float* __restrict__ mbe2,
    const ushort_t* __restrict__ mw3b, const float* __restrict__ mb3,
    const float* __restrict__ mg3, const float* __restrict__ mbe3,
    const float* __restrict__ fcw, const float* __restrict__ fcb,
    float* __restrict__ outp)
{
  __shared__ __align__(16) char smem[18432];
  ushort_t* h2s = (ushort_t*)smem;                   // [128][72]
  float* attL = (float*)smem;                        // [256]  (reuses dead h2s)
  float* part = (float*)(smem + 1024);               // [208]

  const int tid = threadIdx.x;
  const int w = tid >> 6, lane = tid & 63, lg = lane >> 4, lr = lane & 15;
  const int n = blockIdx.x;
  const float LOG2E = 1.4426950408889634f;

  // ---- phase1: h2[m][j] = relu(g2*(h1 @ mw2^T + b2) + be2) -> h2s ----
  // A-frags built in-register from PA2/PB2 (h1 never materialized).
  {
    f32x4 acc1[2][4];
    #pragma unroll
    for (int mt = 0; mt < 2; ++mt)
      #pragma unroll
      for (int jt = 0; jt < 4; ++jt) acc1[mt][jt] = f32x4{0.f, 0.f, 0.f, 0.f};
    bf16x8 a1[2], b1[4];
    {
      const float* pa = &PA2[(size_t)n * 32 + lg * 8];
      float4_t pa0 = *(const float4_t*)pa;
      float4_t pa1 = *(const float4_t*)(pa + 4);
      #pragma unroll
      for (int mt = 0; mt < 2; ++mt) {
        const int m = w * 32 + mt * 16 + lr;
        const float* pb = &PB2[(size_t)m * 32 + lg * 8];
        float4_t pb0 = *(const float4_t*)pb;
        float4_t pb1 = *(const float4_t*)(pb + 4);
        bf16x8 u;
        #pragma unroll
        for (int e = 0; e < 4; ++e) {
          u[e]     = (short)f2b(fmaxf(pa0[e] - pb0[e], 0.f));
          u[4 + e] = (short)f2b(fmaxf(pa1[e] - pb1[e], 0.f));
        }
        a1[mt] = u;
      }
    }
    #pragma unroll
    for (int jt = 0; jt < 4; ++jt)
      b1[jt] = *(const bf16x8*)&mw2b[(jt * 16 + lr) * 32 + lg * 8];
    #pragma unroll
    for (int mt = 0; mt < 2; ++mt)
      #pragma unroll
      for (int jt = 0; jt < 4; ++jt)
        acc1[mt][jt] = __builtin_amdgcn_mfma_f32_16x16x32_bf16(a1[mt], b1[jt], acc1[mt][jt], 0, 0, 0);
    #pragma unroll
    for (int jt = 0; jt < 4; ++jt) {
      const int j = jt * 16 + lr;
      const float g = mg2[j], bv = mb2[j], ev = mbe2[j];
      #pragma unroll
      for (int mt = 0; mt < 2; ++mt)
        #pragma unroll
        for (int r = 0; r < 4; ++r)
          h2s[(w * 32 + mt * 16 + 4 * lg + r) * 72 + jt * 16 + lr] =
              f2b(fmaxf(g * (acc1[mt][jt][r] + bv) + ev, 0.f));
    }
  }
  __syncthreads();

  // ---- phase2 + single-pass no-max softmax (ct-pairs) ----
  float smv[4], wbv[4];
  #pragma unroll
  for (int cp = 0; cp < 2; ++cp) {
    f32x4 acc[8][2];
    #pragma unroll
    for (int mt = 0; mt < 8; ++mt) {
      acc[mt][0] = f32x4{0.f, 0.f, 0.f, 0.f};
      acc[mt][1] = f32x4{0.f, 0.f, 0.f, 0.f};
    }
    #pragma unroll
    for (int ks = 0; ks < 2; ++ks) {
      bf16x8 bfr[2];
      #pragma unroll
      for (int q = 0; q < 2; ++q) {
        const int c = w * 64 + (cp * 2 + q) * 16 + lr;
        bfr[q] = *(const bf16x8*)&mw3b[(size_t)c * 64 + ks * 32 + lg * 8];
      }
      #pragma unroll
      for (int mt = 0; mt < 8; ++mt) {
        bf16x8 af = *(const bf16x8*)&h2s[(mt * 16 + lr) * 72 + ks * 32 + lg * 8];
        acc[mt][0] = __builtin_amdgcn_mfma_f32_16x16x32_bf16(af, bfr[0], acc[mt][0], 0, 0, 0);
        acc[mt][1] = __builtin_amdgcn_mfma_f32_16x16x32_bf16(af, bfr[1], acc[mt][1], 0, 0, 0);
      }
    }
    #pragma unroll
    for (int q = 0; q < 2; ++q) {
      const int ct = cp * 2 + q;
      const int c = w * 64 + ct * 16 + lr;
      const float g = mg3[c], bv = mb3[c], ev = mbe3[c];
      const float gs = g * LOG2E;
      const float cs = (g * bv + ev) * LOG2E;
      f32x4 sm4 = f32x4{0.f, 0.f, 0.f, 0.f};
      f32x4 wb4 = f32x4{0.f, 0.f, 0.f, 0.f};
      #pragma unroll
      for (int mt = 0; mt < 8; ++mt) {
        float4_t bv4 = *(const float4_t*)&BmT[(size_t)c * 128 + mt * 16 + 4 * lg];
        #pragma unroll
        for (int r = 0; r < 4; ++r) {
          float t = fmaf(gs, acc[mt][q][r], cs);
          float p = exp2f(__builtin_amdgcn_fmed3f(t, 0.f, 80.f));
          sm4[r] += p;
          wb4[r] = fmaf(p, bv4[r], wb4[r]);
        }
      }
      smv[ct] = (sm4[0] + sm4[1]) + (sm4[2] + sm4[3]);
      wbv[ct] = (wb4[0] + wb4[1]) + (wb4[2] + wb4[3]);
    }
  }
  // merge the 4 lane-groups (m-partition): plain adds (no max rebase needed)
  #pragma unroll
  for (int st = 16; st <= 32; st <<= 1) {
    #pragma unroll
    for (int ct = 0; ct < 4; ++ct) {
      smv[ct] += __shfl_xor(smv[ct], st, 64);
      wbv[ct] += __shfl_xor(wbv[ct], st, 64);
    }
  }

  __syncthreads();  // all h2s traffic done -> reuse front of smem
  if (lg == 0) {
    #pragma unroll
    for (int ct = 0; ct < 4; ++ct) {
      const int c = w * 64 + ct * 16 + lr;
      attL[c] = A[(size_t)n * 256 + c] - wbv[ct] / smv[ct];
    }
  }
  __syncthreads();

  // ---- fc: out[o] = fcb[o] + sum_c attL[c]*fcw[o][c]; 16 partials per o ----
  {
    const int o = tid >> 4, gp = tid & 15;
    if (o < 13) {
      float s = 0.f;
      #pragma unroll
      for (int i = 0; i < 4; ++i) {
        float4_t av = *(const float4_t*)&attL[gp * 16 + i * 4];
        float4_t wv = *(const float4_t*)&fcw[(size_t)o * 256 + gp * 16 + i * 4];
        #pragma unroll
        for (int e = 0; e < 4; ++e) s = fmaf(av[e], wv[e], s);
      }
      part[o * 16 + gp] = s;
    }
  }
  __syncthreads();
  if (tid < 13) {
    float s = fcb[tid];
    #pragma unroll
    for (int gp = 0; gp < 16; ++gp) s += part[tid * 16 + gp];
    outp[(size_t)n * 13 + tid] = s;
  }
}

extern "C" void kernel_launch(void* const* d_in, const int* in_sizes, int n_in,
                              void* d_out, int out_size, void* d_ws, size_t ws_size,
                              hipStream_t stream)
{
  const float* ext = (const float*)d_in[0];
  const float* lab = (const float*)d_in[1];
  const float* w1a = (const float*)d_in[2];
  const float* b1a = (const float*)d_in[3];
  const float* g1a = (const float*)d_in[4];
  const float* be1a= (const float*)d_in[5];
  const float* w1b = (const float*)d_in[6];
  const float* b1b = (const float*)d_in[7];
  const float* g1b = (const float*)d_in[8];
  const float* be1b= (const float*)d_in[9];
  const float* w2a = (const float*)d_in[10];
  const float* b2a = (const float*)d_in[11];
  const float* g2a = (const float*)d_in[12];
  const float* be2a= (const float*)d_in[13];
  const float* w2b = (const float*)d_in[14];
  const float* b2b = (const float*)d_in[15];
  const float* g2b = (const float*)d_in[16];
  const float* be2b= (const float*)d_in[17];
  const float* mw1 = (const float*)d_in[18];
  const float* mb1 = (const float*)d_in[19];
  const float* mg1 = (const float*)d_in[20];
  const float* mbe1= (const float*)d_in[21];
  const float* mw2 = (const float*)d_in[22];
  const float* mb2 = (const float*)d_in[23];
  const float* mg2 = (const float*)d_in[24];
  const float* mbe2= (const float*)d_in[25];
  const float* mw3 = (const float*)d_in[26];
  const float* mb3 = (const float*)d_in[27];
  const float* mg3 = (const float*)d_in[28];
  const float* mbe3= (const float*)d_in[29];
  const float* fcw = (const float*)d_in[30];
  const float* fcb = (const float*)d_in[31];

  char* ws = (char*)d_ws;
  ushort_t* Y1ab = (ushort_t*)(ws);                       // [0,2M) bf16 2048x512 (dead after enc2)
  float*    PA2  = (float*)(ws);                          // [0,256K) written by proj
  float*    PB2  = (float*)(ws + 262144);                 // [256K,272K)
  float*    Aenc = (float*)(ws + (2u << 20));             // [2M,4M) f32 2048x256
  char* b5 = ws + (4u << 20);
  ushort_t* mw2b = (ushort_t*)(b5);                       // 64x32 bf16 (4KB)
  ushort_t* mw3b = (ushort_t*)(b5 + 4096);                // 256x64 bf16 (32KB)
  ushort_t* Y1bb = (ushort_t*)(b5 + 36864);               // 128x512 bf16 (128KB)
  float*    Benc = (float*)(b5 + 167936);                 // 128x256 f32 (128KB)
  float*    BencT= (float*)(b5 + 299008);                 // 256x128 f32 (128KB)

  enc_mfma<0, 0, 1><<<dim3(34, 8), 256, 0, stream>>>(
      (const void*)ext, (const void*)w1a, b1a, g1a, be1a, (void*)Y1ab,
      (const void*)lab, (const void*)w2a, b2a, g2a, be2a, (void*)Y1bb,
      (float*)nullptr, 512, 352, 32);
  enc_mfma<1, 0, 0><<<dim3(34, 4), 256, 0, stream>>>(
      (const void*)Y1ab, (const void*)w1b, b1b, g1b, be1b, (void*)Aenc,
      (const void*)Y1bb, (const void*)w2b, b2b, g2b, be2b, (void*)Benc,
      BencT, 256, 512, 32);
  proj32<<<281, 256, 0, stream>>>(Aenc, Benc, mw1, mb1, mg1, mbe1, PA2, PB2, 256,
                                  mw2, mw3, mw2b, mw3b);
  main_attn<<<2048, 256, 0, stream>>>(PA2, PB2, Aenc, BencT,
                                      mw2b, mb2, mg2, mbe2, mw3b, mb3, mg3, mbe3,
                                      fcw, fcb, (float*)d_out);
}